// Round 1
// baseline (2606.560 us; speedup 1.0000x reference)
//
#include <hip/hip_runtime.h>
#include <cstdint>
#include <cstddef>

#define IN_F   256
#define HIDC   128
#define OUT_F  256
#define HEADS  4
#define CATF   512

// ---------------- CSR build ----------------
__global__ void init_counts(int* cnt, int N) {
    int i = blockIdx.x * blockDim.x + threadIdx.x;
    if (i < N) cnt[i] = 1;  // self loop contributes 1 in-edge per node
}

__global__ void count_dst(const int* __restrict__ dst, int E, int* cnt) {
    int i = blockIdx.x * blockDim.x + threadIdx.x;
    if (i < E) atomicAdd(&cnt[dst[i]], 1);
}

// single-block exclusive scan over N counts -> indptr[N+1]; pos = copy of starts
__global__ void scan_counts(const int* __restrict__ cnt, int* indptr, int* pos, int N) {
    __shared__ int tmp[1024];
    __shared__ int carry;
    if (threadIdx.x == 0) carry = 0;
    __syncthreads();
    for (int base = 0; base < N; base += 1024) {
        int i = base + (int)threadIdx.x;
        int v = (i < N) ? cnt[i] : 0;
        tmp[threadIdx.x] = v;
        __syncthreads();
        for (int off = 1; off < 1024; off <<= 1) {
            int t = (threadIdx.x >= (unsigned)off) ? tmp[threadIdx.x - off] : 0;
            __syncthreads();
            tmp[threadIdx.x] += t;
            __syncthreads();
        }
        int excl = tmp[threadIdx.x] - v;
        if (i < N) { indptr[i] = carry + excl; pos[i] = carry + excl; }
        __syncthreads();
        if (threadIdx.x == 1023) carry += tmp[1023];
        __syncthreads();
    }
    if (threadIdx.x == 0) indptr[N] = carry;
}

__global__ void scatter_edges(const int* __restrict__ src, const int* __restrict__ dst,
                              int E, int N, int* pos, int* esrc) {
    int i = blockIdx.x * blockDim.x + threadIdx.x;
    int total = E + N;
    if (i >= total) return;
    int s, d;
    if (i < E) { s = src[i]; d = dst[i]; }
    else       { s = i - E;  d = s; }        // self loops appended
    int p = atomicAdd(&pos[d], 1);
    esrc[p] = s;
}

// ---------------- generic fp32 GEMM: C = A[MxK] @ B[KxN] (+bias, act) ----------------
// act: 0 = none, 1 = relu, 2 = elu
#define BM 64
#define BN 64
#define BK 16
__global__ __launch_bounds__(256) void gemm_bias_act(const float* __restrict__ A,
                                                     const float* __restrict__ B,
                                                     const float* __restrict__ bias,
                                                     float* __restrict__ C,
                                                     int M, int N, int K, int act) {
    __shared__ float sA[BK][BM + 1];
    __shared__ float sB[BK][BN + 1];
    int m0 = blockIdx.y * BM, n0 = blockIdx.x * BN;
    int tid = threadIdx.x;
    int tx = tid & 15, ty = tid >> 4;  // 16x16 threads, each 4x4 outputs
    float acc[4][4];
#pragma unroll
    for (int i = 0; i < 4; i++)
#pragma unroll
        for (int j = 0; j < 4; j++) acc[i][j] = 0.f;

    for (int k0 = 0; k0 < K; k0 += BK) {
#pragma unroll
        for (int i = 0; i < 4; i++) {          // A tile 64x16
            int idx = tid + i * 256;
            int r = idx >> 4, c = idx & 15;
            int gm = m0 + r;
            sA[c][r] = (gm < M) ? A[(size_t)gm * K + k0 + c] : 0.f;
        }
#pragma unroll
        for (int i = 0; i < 4; i++) {          // B tile 16x64
            int idx = tid + i * 256;
            int r = idx >> 6, c = idx & 63;
            sB[r][c] = B[(size_t)(k0 + r) * N + n0 + c];
        }
        __syncthreads();
#pragma unroll
        for (int k = 0; k < BK; k++) {
            float a[4], b[4];
#pragma unroll
            for (int i = 0; i < 4; i++) a[i] = sA[k][ty * 4 + i];
#pragma unroll
            for (int j = 0; j < 4; j++) b[j] = sB[k][tx * 4 + j];
#pragma unroll
            for (int i = 0; i < 4; i++)
#pragma unroll
                for (int j = 0; j < 4; j++) acc[i][j] += a[i] * b[j];
        }
        __syncthreads();
    }
#pragma unroll
    for (int i = 0; i < 4; i++) {
        int gm = m0 + ty * 4 + i;
        if (gm >= M) continue;
#pragma unroll
        for (int j = 0; j < 4; j++) {
            int gn = n0 + tx * 4 + j;
            float o = acc[i][j];
            if (bias) o += bias[gn];
            if (act == 1) o = o > 0.f ? o : 0.f;
            else if (act == 2) o = o > 0.f ? o : (expf(o) - 1.f);
            C[(size_t)gm * N + gn] = o;
        }
    }
}

// ---------------- attention coefficients: al_s/al_d [N,H] ----------------
// block = H*64 threads; one block per node; wave w handles head w
__global__ void attn_coef(const float* __restrict__ h, const float* __restrict__ a_src,
                          const float* __restrict__ a_dst, float* __restrict__ al_s,
                          float* __restrict__ al_d, int N, int H, int C) {
    int n = blockIdx.x;
    int w = threadIdx.x >> 6;
    int lane = threadIdx.x & 63;
    float ss = 0.f, sd = 0.f;
    const float* hrow = h + (size_t)n * H * C + (size_t)w * C;
    for (int c = lane; c < C; c += 64) {
        float v = hrow[c];
        ss += v * a_src[w * C + c];
        sd += v * a_dst[w * C + c];
    }
#pragma unroll
    for (int off = 32; off > 0; off >>= 1) {
        ss += __shfl_down(ss, off);
        sd += __shfl_down(sd, off);
    }
    if (lane == 0) {
        al_s[n * H + w] = ss;
        al_d[n * H + w] = sd;
    }
}

// ---------------- GAT aggregation with online softmax ----------------
// one wave per (node, head); CW = C/64 accumulator regs per lane
// act: 1 = elu (+bias), 0 = none (+bias)
template <int CW>
__global__ void gat_aggregate(const float* __restrict__ h, const float* __restrict__ al_s,
                              const float* __restrict__ al_d, const int* __restrict__ indptr,
                              const int* __restrict__ esrc, const float* __restrict__ bias,
                              float* __restrict__ out, int N, int H, int act) {
    const int C = CW * 64;
    int wid = (blockIdx.x * blockDim.x + threadIdx.x) >> 6;
    int lane = threadIdx.x & 63;
    if (wid >= N * H) return;
    int n = wid / H;
    int hh = wid - n * H;

    float m = -1.0e30f, l = 0.f;
    float acc[CW];
#pragma unroll
    for (int j = 0; j < CW; j++) acc[j] = 0.f;

    float ald = al_d[n * H + hh];
    int beg = indptr[n], end = indptr[n + 1];
    for (int idx = beg; idx < end; ++idx) {
        int s = esrc[idx];
        float e = al_s[s * H + hh] + ald;
        e = e > 0.f ? e : 0.2f * e;                 // leaky_relu 0.2
        float mnew = fmaxf(m, e);
        float scale = expf(m - mnew);               // 0 on first iter
        float w = expf(e - mnew);
        l = l * scale + w;
        const float* hrow = h + (size_t)s * H * C + (size_t)hh * C;
#pragma unroll
        for (int j = 0; j < CW; j++) acc[j] = acc[j] * scale + w * hrow[j * 64 + lane];
        m = mnew;
    }
    float inv = 1.f / (l + 1e-16f);
    size_t obase = (size_t)n * H * C + (size_t)hh * C;
#pragma unroll
    for (int j = 0; j < CW; j++) {
        float o = acc[j] * inv + bias[hh * C + j * 64 + lane];
        if (act == 1) o = o > 0.f ? o : (expf(o) - 1.f);  // elu
        out[obase + j * 64 + lane] = o;
    }
}

extern "C" void kernel_launch(void* const* d_in, const int* in_sizes, int n_in,
                              void* d_out, int out_size, void* d_ws, size_t ws_size,
                              hipStream_t stream) {
    const float* x   = (const float*)d_in[0];
    const int*   ei  = (const int*)d_in[1];
    const float* W1  = (const float*)d_in[2];
    const float* as1 = (const float*)d_in[3];
    const float* ad1 = (const float*)d_in[4];
    const float* b1  = (const float*)d_in[5];
    const float* W2  = (const float*)d_in[6];
    const float* as2 = (const float*)d_in[7];
    const float* ad2 = (const float*)d_in[8];
    const float* b2  = (const float*)d_in[9];
    const float* W3  = (const float*)d_in[10];
    const float* as3 = (const float*)d_in[11];
    const float* ad3 = (const float*)d_in[12];
    const float* b3  = (const float*)d_in[13];
    const float* M1  = (const float*)d_in[14];
    const float* mb1 = (const float*)d_in[15];
    const float* M2  = (const float*)d_in[16];
    const float* mb2 = (const float*)d_in[17];
    const float* M3  = (const float*)d_in[18];
    const float* mb3 = (const float*)d_in[19];
    float* out = (float*)d_out;

    const int N = in_sizes[0] / IN_F;  // 50000
    const int E = in_sizes[1] / 2;     // 800000
    const int* src = ei;
    const int* dst = ei + E;

    char* ws = (char*)d_ws;
    float* bufA  = (float*)ws; ws += (size_t)N * CATF * sizeof(float);
    float* bufB  = (float*)ws; ws += (size_t)N * CATF * sizeof(float);
    float* al_s  = (float*)ws; ws += (size_t)N * HEADS * sizeof(float);
    float* al_d  = (float*)ws; ws += (size_t)N * HEADS * sizeof(float);
    int* cnt     = (int*)ws;   ws += (size_t)N * sizeof(int);
    int* pos     = (int*)ws;   ws += (size_t)N * sizeof(int);
    int* indptr  = (int*)ws;   ws += (size_t)(N + 1) * sizeof(int);
    int* esrc    = (int*)ws;   ws += (size_t)(E + N) * sizeof(int);

    // ---- CSR build (by dst), self-loops appended ----
    init_counts<<<(N + 255) / 256, 256, 0, stream>>>(cnt, N);
    count_dst<<<(E + 255) / 256, 256, 0, stream>>>(dst, E, cnt);
    scan_counts<<<1, 1024, 0, stream>>>(cnt, indptr, pos, N);
    scatter_edges<<<(E + N + 255) / 256, 256, 0, stream>>>(src, dst, E, N, pos, esrc);

    auto gemm = [&](const float* A, const float* B, const float* bias, float* C,
                    int M, int Nc, int K, int act) {
        dim3 grid(Nc / BN, (M + BM - 1) / BM);
        gemm_bias_act<<<grid, 256, 0, stream>>>(A, B, bias, C, M, Nc, K, act);
    };

    // ---- GAT layer 1: x[N,256] -> bufB[N,512], ELU ----
    gemm(x, W1, nullptr, bufA, N, CATF, IN_F, 0);
    attn_coef<<<N, HEADS * 64, 0, stream>>>(bufA, as1, ad1, al_s, al_d, N, HEADS, HIDC);
    gat_aggregate<2><<<(N * HEADS + 3) / 4, 256, 0, stream>>>(bufA, al_s, al_d, indptr, esrc,
                                                              b1, bufB, N, HEADS, 1);

    // ---- GAT layer 2: bufB[N,512] -> bufB[N,512], ELU ----
    gemm(bufB, W2, nullptr, bufA, N, CATF, CATF, 0);
    attn_coef<<<N, HEADS * 64, 0, stream>>>(bufA, as2, ad2, al_s, al_d, N, HEADS, HIDC);
    gat_aggregate<2><<<(N * HEADS + 3) / 4, 256, 0, stream>>>(bufA, al_s, al_d, indptr, esrc,
                                                              b2, bufB, N, HEADS, 1);

    // ---- GAT layer 3: bufB[N,512] -> bufB[N,256], 1 head, no act ----
    gemm(bufB, W3, nullptr, bufA, N, OUT_F, CATF, 0);
    attn_coef<<<N, 64, 0, stream>>>(bufA, as3, ad3, al_s, al_d, N, 1, OUT_F);
    gat_aggregate<4><<<(N + 3) / 4, 256, 0, stream>>>(bufA, al_s, al_d, indptr, esrc,
                                                      b3, bufB, N, 1, 0);

    // ---- MLP: relu(h@M1+mb1) -> relu(@M2+mb2) -> @M3+mb3 ----
    gemm(bufB, M1, mb1, bufA, N, 2 * HIDC, OUT_F, 1);  // [N,256]
    gemm(bufA, M2, mb2, bufB, N, HIDC, 2 * HIDC, 1);   // [N,128]
    gemm(bufB, M3, mb3, out, N, OUT_F, HIDC, 0);       // [N,256]
}

// Round 2
// 1712.598 us; speedup vs baseline: 1.5220x; 1.5220x over previous
//
#include <hip/hip_runtime.h>
#include <cstdint>
#include <cstddef>

#define HEADS  4
#define HIDC   128
#define CATF   512
#define IN_F   256
#define OUT_F  256

typedef short bf16x8 __attribute__((ext_vector_type(8)));
typedef float f32x4  __attribute__((ext_vector_type(4)));

__device__ __forceinline__ short f2bf(float f) {
    unsigned u = __builtin_bit_cast(unsigned, f);
    u = u + 0x7fffu + ((u >> 16) & 1u);   // round-to-nearest-even
    return (short)(u >> 16);
}
__device__ __forceinline__ float bf2f(short s) {
    return __builtin_bit_cast(float, ((unsigned)(unsigned short)s) << 16);
}
__device__ __forceinline__ float bf2f_lo(unsigned u) { return __builtin_bit_cast(float, u << 16); }
__device__ __forceinline__ float bf2f_hi(unsigned u) { return __builtin_bit_cast(float, u & 0xffff0000u); }
__device__ __forceinline__ unsigned pack2(short a, short b) {
    return (unsigned)(unsigned short)a | ((unsigned)(unsigned short)b << 16);
}

__device__ __forceinline__ void async16(const void* g, void* l) {
    __builtin_amdgcn_global_load_lds((const __attribute__((address_space(1))) void*)g,
                                     (__attribute__((address_space(3))) void*)l, 16, 0, 0);
}

// ---------------- CSR build ----------------
__global__ void init_counts(int* cnt, int N) {
    int i = blockIdx.x * blockDim.x + threadIdx.x;
    if (i < N) cnt[i] = 1;  // self loop
}

__global__ void count_dst(const int* __restrict__ dst, int E, int* cnt) {
    int i = blockIdx.x * blockDim.x + threadIdx.x;
    if (i < E) atomicAdd(&cnt[dst[i]], 1);
}

__global__ void scan_counts(const int* __restrict__ cnt, int* indptr, int* pos, int N) {
    __shared__ int tmp[1024];
    __shared__ int carry;
    if (threadIdx.x == 0) carry = 0;
    __syncthreads();
    for (int base = 0; base < N; base += 1024) {
        int i = base + (int)threadIdx.x;
        int v = (i < N) ? cnt[i] : 0;
        tmp[threadIdx.x] = v;
        __syncthreads();
        for (int off = 1; off < 1024; off <<= 1) {
            int t = (threadIdx.x >= (unsigned)off) ? tmp[threadIdx.x - off] : 0;
            __syncthreads();
            tmp[threadIdx.x] += t;
            __syncthreads();
        }
        int excl = tmp[threadIdx.x] - v;
        if (i < N) { indptr[i] = carry + excl; pos[i] = carry + excl; }
        __syncthreads();
        if (threadIdx.x == 1023) carry += tmp[1023];
        __syncthreads();
    }
    if (threadIdx.x == 0) indptr[N] = carry;
}

__global__ void scatter_edges(const int* __restrict__ src, const int* __restrict__ dst,
                              int E, int N, int* pos, int* esrc) {
    int i = blockIdx.x * blockDim.x + threadIdx.x;
    int total = E + N;
    if (i >= total) return;
    int s, d;
    if (i < E) { s = src[i]; d = dst[i]; }
    else       { s = i - E;  d = s; }
    int p = atomicAdd(&pos[d], 1);
    esrc[p] = s;
}

// ---------------- fp32 -> (hi,lo) bf16 planes ----------------
__global__ void conv_split(const float* __restrict__ in, short* __restrict__ hi,
                           short* __restrict__ lo, long n2) {  // n2 = n/2
    long i = (long)blockIdx.x * blockDim.x + threadIdx.x;
    if (i >= n2) return;
    float2 v = ((const float2*)in)[i];
    short h0 = f2bf(v.x), h1 = f2bf(v.y);
    short l0 = f2bf(v.x - bf2f(h0)), l1 = f2bf(v.y - bf2f(h1));
    ((unsigned*)hi)[i] = pack2(h0, h1);
    ((unsigned*)lo)[i] = pack2(l0, l1);
}

// W[K,N] fp32 -> Bt_hi/Bt_lo [N,K] bf16 (transposed)
__global__ void conv_w_t(const float* __restrict__ W, short* __restrict__ hi,
                         short* __restrict__ lo, int K, int N) {
    int idx = blockIdx.x * blockDim.x + threadIdx.x;
    if (idx >= K * N) return;
    int n = idx / K, k = idx - n * K;
    float v = W[(size_t)k * N + n];
    short h = f2bf(v);
    hi[(size_t)n * K + k] = h;
    lo[(size_t)n * K + k] = f2bf(v - bf2f(h));
}

// ---------------- bf16x3 MFMA GEMM: C = A @ Bt^T ----------------
// A (hi/lo) [M,K] row-major bf16; Bt (hi/lo) [N,K] row-major bf16.
// MODE 0: out -> hi/lo bf16 planes;  MODE 1: out -> fp32.
// act: 0 none, 1 relu. bias may be null.
#define TM 128
#define TN 128
#define TK 32
template <int MODE>
__global__ __launch_bounds__(256) void gemm_bt(
        const short* __restrict__ Ah, const short* __restrict__ Al,
        const short* __restrict__ Bh, const short* __restrict__ Bl,
        const float* __restrict__ bias,
        short* __restrict__ out_hi, short* __restrict__ out_lo, float* __restrict__ out_f,
        int M, int N, int K, int act) {
    __shared__ __align__(16) short sAh[TM * TK], sAl[TM * TK], sBh[TN * TK], sBl[TN * TK];
    int tid = threadIdx.x;
    int wave = tid >> 6, lane = tid & 63;
    int m0 = blockIdx.y * TM, n0 = blockIdx.x * TN;
    int wm = wave >> 1, wn = wave & 1;           // 2x2 waves, each 64x64
    int srow = lane >> 2;                        // staging: row within 16-row chunk
    int skel = (lane & 3) * 8;                   // staging: k element 0,8,16,24
    int fr = lane & 15, quad = lane >> 4;        // fragment row/col, k-quad

    f32x4 acc[4][4];
#pragma unroll
    for (int i = 0; i < 4; i++)
#pragma unroll
        for (int j = 0; j < 4; j++) acc[i][j] = (f32x4){0.f, 0.f, 0.f, 0.f};

    for (int k0 = 0; k0 < K; k0 += TK) {
        __syncthreads();
#pragma unroll
        for (int c = 0; c < 2; c++) {
            int chunk = wave * 2 + c;            // 0..7 (16 rows each)
            int r = chunk * 16 + srow;
            int gmA = m0 + r; if (gmA >= M) gmA = M - 1;
            int gnB = n0 + r;
            size_t aoff = (size_t)gmA * K + k0 + skel;
            size_t boff = (size_t)gnB * K + k0 + skel;
            int ldso = chunk * 512;              // shorts (1 KB chunks)
            async16(Ah + aoff, &sAh[ldso]);
            async16(Al + aoff, &sAl[ldso]);
            async16(Bh + boff, &sBh[ldso]);
            async16(Bl + boff, &sBl[ldso]);
        }
        __syncthreads();

        bf16x8 fah[4], fal[4], fbh[4], fbl[4];
#pragma unroll
        for (int i = 0; i < 4; i++) {
            int ra = (wm * 64 + i * 16 + fr) * TK + quad * 8;
            int rb = (wn * 64 + i * 16 + fr) * TK + quad * 8;
            fah[i] = *(const bf16x8*)&sAh[ra];
            fal[i] = *(const bf16x8*)&sAl[ra];
            fbh[i] = *(const bf16x8*)&sBh[rb];
            fbl[i] = *(const bf16x8*)&sBl[rb];
        }
#pragma unroll
        for (int i = 0; i < 4; i++)
#pragma unroll
            for (int j = 0; j < 4; j++) {
                acc[i][j] = __builtin_amdgcn_mfma_f32_16x16x32_bf16(fah[i], fbl[j], acc[i][j], 0, 0, 0);
                acc[i][j] = __builtin_amdgcn_mfma_f32_16x16x32_bf16(fal[i], fbh[j], acc[i][j], 0, 0, 0);
                acc[i][j] = __builtin_amdgcn_mfma_f32_16x16x32_bf16(fah[i], fbh[j], acc[i][j], 0, 0, 0);
            }
    }

#pragma unroll
    for (int i = 0; i < 4; i++)
#pragma unroll
        for (int r = 0; r < 4; r++) {
            int gm = m0 + wm * 64 + i * 16 + quad * 4 + r;
            if (gm >= M) continue;
#pragma unroll
            for (int j = 0; j < 4; j++) {
                int gn = n0 + wn * 64 + j * 16 + fr;
                float v = acc[i][j][r];
                if (bias) v += bias[gn];
                if (act == 1) v = fmaxf(v, 0.f);
                size_t o = (size_t)gm * N + gn;
                if (MODE == 0) {
                    short h = f2bf(v);
                    out_hi[o] = h;
                    out_lo[o] = f2bf(v - bf2f(h));
                } else {
                    out_f[o] = v;
                }
            }
        }
}

// ---------------- attention coefficients ----------------
__global__ void attn_coef(const short* __restrict__ hhi, const short* __restrict__ hlo,
                          const float* __restrict__ a_src, const float* __restrict__ a_dst,
                          float* __restrict__ al_s, float* __restrict__ al_d,
                          int N, int H, int C) {
    int n = blockIdx.x;
    int w = threadIdx.x >> 6;
    int lane = threadIdx.x & 63;
    size_t base = ((size_t)n * H + w) * C;
    float ss = 0.f, sd = 0.f;
    for (int c = lane; c < C; c += 64) {
        float v = bf2f(hhi[base + c]) + bf2f(hlo[base + c]);
        ss += v * a_src[w * C + c];
        sd += v * a_dst[w * C + c];
    }
#pragma unroll
    for (int off = 32; off > 0; off >>= 1) {
        ss += __shfl_down(ss, off);
        sd += __shfl_down(sd, off);
    }
    if (lane == 0) {
        al_s[n * H + w] = ss;
        al_d[n * H + w] = sd;
    }
}

// ---------------- GAT aggregation (online softmax), hi/lo planes ----------------
template <int CW>  // elements per lane; C = CW*64
__global__ void gat_aggregate(const short* __restrict__ hhi, const short* __restrict__ hlo,
                              const float* __restrict__ al_s, const float* __restrict__ al_d,
                              const int* __restrict__ indptr, const int* __restrict__ esrc,
                              const float* __restrict__ bias,
                              short* __restrict__ ohi, short* __restrict__ olo,
                              int N, int H, int act) {
    const int C = CW * 64;
    const int P = CW / 2;
    int wid = (blockIdx.x * blockDim.x + threadIdx.x) >> 6;
    int lane = threadIdx.x & 63;
    if (wid >= N * H) return;
    int n = wid / H;
    int hh = wid - n * H;

    float m = -1.0e30f, l = 0.f;
    float acc[CW];
#pragma unroll
    for (int j = 0; j < CW; j++) acc[j] = 0.f;

    float ald = al_d[n * H + hh];
    int beg = indptr[n], end = indptr[n + 1];
    for (int idx = beg; idx < end; ++idx) {
        int s = esrc[idx];
        float e = al_s[s * H + hh] + ald;
        e = e > 0.f ? e : 0.2f * e;
        float mnew = fmaxf(m, e);
        float scale = expf(m - mnew);
        float w = expf(e - mnew);
        l = l * scale + w;
        size_t base = ((size_t)s * H + hh) * C + lane * CW;
        const unsigned* ph = (const unsigned*)(hhi + base);
        const unsigned* pl = (const unsigned*)(hlo + base);
#pragma unroll
        for (int p = 0; p < P; p++) {
            unsigned uh = ph[p], ul = pl[p];
            float v0 = bf2f_lo(uh) + bf2f_lo(ul);
            float v1 = bf2f_hi(uh) + bf2f_hi(ul);
            acc[2 * p]     = acc[2 * p]     * scale + w * v0;
            acc[2 * p + 1] = acc[2 * p + 1] * scale + w * v1;
        }
        m = mnew;
    }
    float inv = 1.f / (l + 1e-16f);
    size_t ob = ((size_t)n * H + hh) * C + lane * CW;
#pragma unroll
    for (int p = 0; p < P; p++) {
        float o0 = acc[2 * p]     * inv + bias[hh * C + lane * CW + 2 * p];
        float o1 = acc[2 * p + 1] * inv + bias[hh * C + lane * CW + 2 * p + 1];
        if (act == 1) {
            o0 = o0 > 0.f ? o0 : (expf(o0) - 1.f);
            o1 = o1 > 0.f ? o1 : (expf(o1) - 1.f);
        }
        short h0 = f2bf(o0), h1 = f2bf(o1);
        short l0 = f2bf(o0 - bf2f(h0)), l1 = f2bf(o1 - bf2f(h1));
        ((unsigned*)(ohi + ob))[p] = pack2(h0, h1);
        ((unsigned*)(olo + ob))[p] = pack2(l0, l1);
    }
}

extern "C" void kernel_launch(void* const* d_in, const int* in_sizes, int n_in,
                              void* d_out, int out_size, void* d_ws, size_t ws_size,
                              hipStream_t stream) {
    const float* x   = (const float*)d_in[0];
    const int*   ei  = (const int*)d_in[1];
    const float* W1  = (const float*)d_in[2];
    const float* as1 = (const float*)d_in[3];
    const float* ad1 = (const float*)d_in[4];
    const float* b1  = (const float*)d_in[5];
    const float* W2  = (const float*)d_in[6];
    const float* as2 = (const float*)d_in[7];
    const float* ad2 = (const float*)d_in[8];
    const float* b2  = (const float*)d_in[9];
    const float* W3  = (const float*)d_in[10];
    const float* as3 = (const float*)d_in[11];
    const float* ad3 = (const float*)d_in[12];
    const float* b3  = (const float*)d_in[13];
    const float* M1  = (const float*)d_in[14];
    const float* mb1 = (const float*)d_in[15];
    const float* M2  = (const float*)d_in[16];
    const float* mb2 = (const float*)d_in[17];
    const float* M3  = (const float*)d_in[18];
    const float* mb3 = (const float*)d_in[19];
    float* out = (float*)d_out;

    const int N = in_sizes[0] / IN_F;   // 50000
    const int E = in_sizes[1] / 2;      // 800000
    const int* src = ei;
    const int* dst = ei + E;

    char* ws = (char*)d_ws;
    auto alloc = [&](size_t bytes) { char* p = ws; ws += (bytes + 255) & ~(size_t)255; return p; };
    short* P1h = (short*)alloc((size_t)N * CATF * 2);
    short* P1l = (short*)alloc((size_t)N * CATF * 2);
    short* P2h = (short*)alloc((size_t)N * CATF * 2);
    short* P2l = (short*)alloc((size_t)N * CATF * 2);
    float* al_s = (float*)alloc((size_t)N * HEADS * 4);
    float* al_d = (float*)alloc((size_t)N * HEADS * 4);
    int* cnt    = (int*)alloc((size_t)N * 4);
    int* pos    = (int*)alloc((size_t)N * 4);
    int* indptr = (int*)alloc((size_t)(N + 1) * 4);
    int* esrc   = (int*)alloc((size_t)(E + N) * 4);
    // transposed bf16 weights (hi/lo)
    auto walloc = [&](int k, int n, short*& h, short*& l) {
        h = (short*)alloc((size_t)k * n * 2);
        l = (short*)alloc((size_t)k * n * 2);
    };
    short *W1h, *W1l, *W2h, *W2l, *W3h, *W3l, *M1h, *M1l, *M2h, *M2l, *M3h, *M3l;
    walloc(IN_F, CATF, W1h, W1l);
    walloc(CATF, CATF, W2h, W2l);
    walloc(CATF, OUT_F, W3h, W3l);
    walloc(OUT_F, 2 * HIDC, M1h, M1l);
    walloc(2 * HIDC, HIDC, M2h, M2l);
    walloc(HIDC, OUT_F, M3h, M3l);

    // ---- CSR build ----
    init_counts<<<(N + 255) / 256, 256, 0, stream>>>(cnt, N);
    count_dst<<<(E + 255) / 256, 256, 0, stream>>>(dst, E, cnt);
    scan_counts<<<1, 1024, 0, stream>>>(cnt, indptr, pos, N);
    scatter_edges<<<(E + N + 255) / 256, 256, 0, stream>>>(src, dst, E, N, pos, esrc);

    // ---- weight conversion + transpose ----
    auto convw = [&](const float* W, short* h, short* l, int K, int Nc) {
        conv_w_t<<<(K * Nc + 255) / 256, 256, 0, stream>>>(W, h, l, K, Nc);
    };
    convw(W1, W1h, W1l, IN_F, CATF);
    convw(W2, W2h, W2l, CATF, CATF);
    convw(W3, W3h, W3l, CATF, OUT_F);
    convw(M1, M1h, M1l, OUT_F, 2 * HIDC);
    convw(M2, M2h, M2l, 2 * HIDC, HIDC);
    convw(M3, M3h, M3l, HIDC, OUT_F);

    auto gemm_hl = [&](const short* Ahp, const short* Alp, const short* Bhp, const short* Blp,
                       const float* bias, short* oh, short* ol, int M, int Nc, int K, int act) {
        dim3 grid(Nc / TN, (M + TM - 1) / TM);
        gemm_bt<0><<<grid, 256, 0, stream>>>(Ahp, Alp, Bhp, Blp, bias, oh, ol, nullptr, M, Nc, K, act);
    };

    // ---- input conversion: x -> P2 [N,256] ----
    conv_split<<<((long)N * IN_F / 2 + 255) / 256, 256, 0, stream>>>(x, P2h, P2l, (long)N * IN_F / 2);

    // ---- GAT layer 1 ----
    gemm_hl(P2h, P2l, W1h, W1l, nullptr, P1h, P1l, N, CATF, IN_F, 0);
    attn_coef<<<N, HEADS * 64, 0, stream>>>(P1h, P1l, as1, ad1, al_s, al_d, N, HEADS, HIDC);
    gat_aggregate<2><<<(N * HEADS + 3) / 4, 256, 0, stream>>>(P1h, P1l, al_s, al_d, indptr, esrc,
                                                              b1, P2h, P2l, N, HEADS, 1);
    // ---- GAT layer 2 ----
    gemm_hl(P2h, P2l, W2h, W2l, nullptr, P1h, P1l, N, CATF, CATF, 0);
    attn_coef<<<N, HEADS * 64, 0, stream>>>(P1h, P1l, as2, ad2, al_s, al_d, N, HEADS, HIDC);
    gat_aggregate<2><<<(N * HEADS + 3) / 4, 256, 0, stream>>>(P1h, P1l, al_s, al_d, indptr, esrc,
                                                              b2, P2h, P2l, N, HEADS, 1);
    // ---- GAT layer 3 (1 head, C=256, no ELU) ----
    gemm_hl(P2h, P2l, W3h, W3l, nullptr, P1h, P1l, N, OUT_F, CATF, 0);
    attn_coef<<<N, 64, 0, stream>>>(P1h, P1l, as3, ad3, al_s, al_d, N, 1, OUT_F);
    gat_aggregate<4><<<(N + 3) / 4, 256, 0, stream>>>(P1h, P1l, al_s, al_d, indptr, esrc,
                                                      b3, P2h, P2l, N, 1, 0);
    // ---- MLP ----
    gemm_hl(P2h, P2l, M1h, M1l, mb1, P1h, P1l, N, 2 * HIDC, OUT_F, 1);    // relu
    gemm_hl(P1h, P1l, M2h, M2l, mb2, P2h, P2l, N, HIDC, 2 * HIDC, 1);     // relu
    {
        dim3 grid(OUT_F / TN, (N + TM - 1) / TM);
        gemm_bt<1><<<grid, 256, 0, stream>>>(P2h, P2l, M3h, M3l, mb3, nullptr, nullptr, out,
                                             N, OUT_F, HIDC, 0);
    }
}

// Round 3
// 1396.379 us; speedup vs baseline: 1.8667x; 1.2265x over previous
//
#include <hip/hip_runtime.h>
#include <cstdint>
#include <cstddef>

#define HEADS  4
#define HIDC   128
#define CATF   512
#define IN_F   256
#define OUT_F  256

typedef short bf16x8 __attribute__((ext_vector_type(8)));
typedef float f32x4  __attribute__((ext_vector_type(4)));

__device__ __forceinline__ short f2bf(float f) {
    unsigned u = __builtin_bit_cast(unsigned, f);
    u = u + 0x7fffu + ((u >> 16) & 1u);   // round-to-nearest-even
    return (short)(u >> 16);
}
__device__ __forceinline__ float bf2f(short s) {
    return __builtin_bit_cast(float, ((unsigned)(unsigned short)s) << 16);
}
__device__ __forceinline__ unsigned pack2(short a, short b) {
    return (unsigned)(unsigned short)a | ((unsigned)(unsigned short)b << 16);
}

__device__ __forceinline__ void async16(const void* g, void* l) {
    __builtin_amdgcn_global_load_lds((const __attribute__((address_space(1))) void*)g,
                                     (__attribute__((address_space(3))) void*)l, 16, 0, 0);
}

// ---------------- CSR build ----------------
__global__ void init_counts(int* cnt, int N) {
    int i = blockIdx.x * blockDim.x + threadIdx.x;
    if (i < N) cnt[i] = 1;  // self loop
}

__global__ void count_dst(const int* __restrict__ dst, int E, int* cnt) {
    int i = blockIdx.x * blockDim.x + threadIdx.x;
    if (i < E) atomicAdd(&cnt[dst[i]], 1);
}

__global__ void scan_counts(const int* __restrict__ cnt, int* indptr, int* pos, int N) {
    __shared__ int tmp[1024];
    __shared__ int carry;
    if (threadIdx.x == 0) carry = 0;
    __syncthreads();
    for (int base = 0; base < N; base += 1024) {
        int i = base + (int)threadIdx.x;
        int v = (i < N) ? cnt[i] : 0;
        tmp[threadIdx.x] = v;
        __syncthreads();
        for (int off = 1; off < 1024; off <<= 1) {
            int t = (threadIdx.x >= (unsigned)off) ? tmp[threadIdx.x - off] : 0;
            __syncthreads();
            tmp[threadIdx.x] += t;
            __syncthreads();
        }
        int excl = tmp[threadIdx.x] - v;
        if (i < N) { indptr[i] = carry + excl; pos[i] = carry + excl; }
        __syncthreads();
        if (threadIdx.x == 1023) carry += tmp[1023];
        __syncthreads();
    }
    if (threadIdx.x == 0) indptr[N] = carry;
}

__global__ void scatter_edges(const int* __restrict__ src, const int* __restrict__ dst,
                              int E, int N, int* pos, int* esrc) {
    int i = blockIdx.x * blockDim.x + threadIdx.x;
    int total = E + N;
    if (i >= total) return;
    int s, d;
    if (i < E) { s = src[i]; d = dst[i]; }
    else       { s = i - E;  d = s; }
    int p = atomicAdd(&pos[d], 1);
    esrc[p] = s;
}

// ---------------- fp32 -> (hi,lo) bf16 planes ----------------
__global__ void conv_split(const float* __restrict__ in, short* __restrict__ hi,
                           short* __restrict__ lo, long n2) {  // n2 = n/2
    long i = (long)blockIdx.x * blockDim.x + threadIdx.x;
    if (i >= n2) return;
    float2 v = ((const float2*)in)[i];
    short h0 = f2bf(v.x), h1 = f2bf(v.y);
    short l0 = f2bf(v.x - bf2f(h0)), l1 = f2bf(v.y - bf2f(h1));
    ((unsigned*)hi)[i] = pack2(h0, h1);
    ((unsigned*)lo)[i] = pack2(l0, l1);
}

// W[K,N] fp32 -> Bt_hi/Bt_lo [N,K] bf16 (transposed)
__global__ void conv_w_t(const float* __restrict__ W, short* __restrict__ hi,
                         short* __restrict__ lo, int K, int N) {
    int idx = blockIdx.x * blockDim.x + threadIdx.x;
    if (idx >= K * N) return;
    int n = idx / K, k = idx - n * K;
    float v = W[(size_t)k * N + n];
    short h = f2bf(v);
    hi[(size_t)n * K + k] = h;
    lo[(size_t)n * K + k] = f2bf(v - bf2f(h));
}

// ---------------- bf16x3 MFMA GEMM: C = A @ Bt^T ----------------
// MODE 0: out -> hi/lo bf16 planes;  MODE 1: out -> fp32.
#define TM 128
#define TN 128
#define TK 32
template <int MODE>
__global__ __launch_bounds__(256) void gemm_bt(
        const short* __restrict__ Ah, const short* __restrict__ Al,
        const short* __restrict__ Bh, const short* __restrict__ Bl,
        const float* __restrict__ bias,
        short* __restrict__ out_hi, short* __restrict__ out_lo, float* __restrict__ out_f,
        int M, int N, int K, int act) {
    __shared__ __align__(16) short sAh[TM * TK], sAl[TM * TK], sBh[TN * TK], sBl[TN * TK];
    int tid = threadIdx.x;
    int wave = tid >> 6, lane = tid & 63;
    int m0 = blockIdx.y * TM, n0 = blockIdx.x * TN;
    int wm = wave >> 1, wn = wave & 1;           // 2x2 waves, each 64x64
    int srow = lane >> 2;
    int skel = (lane & 3) * 8;
    int fr = lane & 15, quad = lane >> 4;

    f32x4 acc[4][4];
#pragma unroll
    for (int i = 0; i < 4; i++)
#pragma unroll
        for (int j = 0; j < 4; j++) acc[i][j] = (f32x4){0.f, 0.f, 0.f, 0.f};

    for (int k0 = 0; k0 < K; k0 += TK) {
        __syncthreads();
#pragma unroll
        for (int c = 0; c < 2; c++) {
            int chunk = wave * 2 + c;
            int r = chunk * 16 + srow;
            int gmA = m0 + r; if (gmA >= M) gmA = M - 1;
            int gnB = n0 + r;
            size_t aoff = (size_t)gmA * K + k0 + skel;
            size_t boff = (size_t)gnB * K + k0 + skel;
            int ldso = chunk * 512;
            async16(Ah + aoff, &sAh[ldso]);
            async16(Al + aoff, &sAl[ldso]);
            async16(Bh + boff, &sBh[ldso]);
            async16(Bl + boff, &sBl[ldso]);
        }
        __syncthreads();

        bf16x8 fah[4], fal[4], fbh[4], fbl[4];
#pragma unroll
        for (int i = 0; i < 4; i++) {
            int ra = (wm * 64 + i * 16 + fr) * TK + quad * 8;
            int rb = (wn * 64 + i * 16 + fr) * TK + quad * 8;
            fah[i] = *(const bf16x8*)&sAh[ra];
            fal[i] = *(const bf16x8*)&sAl[ra];
            fbh[i] = *(const bf16x8*)&sBh[rb];
            fbl[i] = *(const bf16x8*)&sBl[rb];
        }
#pragma unroll
        for (int i = 0; i < 4; i++)
#pragma unroll
            for (int j = 0; j < 4; j++) {
                acc[i][j] = __builtin_amdgcn_mfma_f32_16x16x32_bf16(fah[i], fbl[j], acc[i][j], 0, 0, 0);
                acc[i][j] = __builtin_amdgcn_mfma_f32_16x16x32_bf16(fal[i], fbh[j], acc[i][j], 0, 0, 0);
                acc[i][j] = __builtin_amdgcn_mfma_f32_16x16x32_bf16(fah[i], fbh[j], acc[i][j], 0, 0, 0);
            }
    }

#pragma unroll
    for (int i = 0; i < 4; i++)
#pragma unroll
        for (int r = 0; r < 4; r++) {
            int gm = m0 + wm * 64 + i * 16 + quad * 4 + r;
            if (gm >= M) continue;
#pragma unroll
            for (int j = 0; j < 4; j++) {
                int gn = n0 + wn * 64 + j * 16 + fr;
                float v = acc[i][j][r];
                if (bias) v += bias[gn];
                if (act == 1) v = fmaxf(v, 0.f);
                size_t o = (size_t)gm * N + gn;
                if (MODE == 0) {
                    short h = f2bf(v);
                    out_hi[o] = h;
                    out_lo[o] = f2bf(v - bf2f(h));
                } else {
                    out_f[o] = v;
                }
            }
        }
}

// ---------------- attention coefficients (fp32 h) ----------------
__global__ void attn_coef_f(const float* __restrict__ h, const float* __restrict__ a_src,
                            const float* __restrict__ a_dst, float* __restrict__ al_s,
                            float* __restrict__ al_d, int N, int H, int C) {
    int n = blockIdx.x;
    int w = threadIdx.x >> 6;
    int lane = threadIdx.x & 63;
    size_t base = ((size_t)n * H + w) * C;
    float ss = 0.f, sd = 0.f;
    for (int c = lane; c < C; c += 64) {
        float v = h[base + c];
        ss += v * a_src[w * C + c];
        sd += v * a_dst[w * C + c];
    }
#pragma unroll
    for (int off = 32; off > 0; off >>= 1) {
        ss += __shfl_down(ss, off);
        sd += __shfl_down(sd, off);
    }
    if (lane == 0) {
        al_s[n * H + w] = ss;
        al_d[n * H + w] = sd;
    }
}

// ---------------- merged-head GAT aggregation ----------------
// one wave per node; lane owns CT consecutive floats of the C_ALL = CT*64 row.
// lanes-per-head = 64/H; each lane computes the softmax chain only for ITS head.
// No max subtraction (exp(e) directly; |e| << 88 for this data; clamp 60 for safety).
template <int CT, int H>
__global__ void gat_aggregate_m(const float* __restrict__ h,
                                const float* __restrict__ al_s, const float* __restrict__ al_d,
                                const int* __restrict__ indptr, const int* __restrict__ esrc,
                                const float* __restrict__ bias,
                                short* __restrict__ ohi, short* __restrict__ olo,
                                int N, int act) {
    const int C_ALL = CT * 64;
    int n = (blockIdx.x * blockDim.x + threadIdx.x) >> 6;
    int lane = threadIdx.x & 63;
    if (n >= N) return;
    int head = (lane * H) >> 6;            // which head this lane's elements belong to
    float ald = al_d[n * H + head];
    float l = 0.f;
    float acc[CT];
#pragma unroll
    for (int k = 0; k < CT; k++) acc[k] = 0.f;

    int beg = indptr[n], end = indptr[n + 1];   // >=1 edge (self loop)
    int s = esrc[beg];
    float as = al_s[s * H + head];
    for (int idx = beg; idx < end; ++idx) {
        int s_cur = s;
        float as_cur = as;
        if (idx + 1 < end) {                    // prefetch next edge's scalars
            s = esrc[idx + 1];
            as = al_s[s * H + head];
        }
        float e = as_cur + ald;
        e = e > 0.f ? e : 0.2f * e;             // leaky_relu 0.2
        e = fminf(e, 60.f);
        float w = __expf(e);
        l += w;
        const float4* p = (const float4*)(h + (size_t)s_cur * C_ALL + lane * CT);
#pragma unroll
        for (int q = 0; q < CT / 4; q++) {
            float4 v = p[q];
            acc[4 * q + 0] += w * v.x;
            acc[4 * q + 1] += w * v.y;
            acc[4 * q + 2] += w * v.z;
            acc[4 * q + 3] += w * v.w;
        }
    }
    float inv = 1.f / (l + 1e-16f);
    size_t ob = (size_t)n * C_ALL + lane * CT;
    const float* bp = bias + lane * CT;
#pragma unroll
    for (int k = 0; k < CT; k += 2) {
        float o0 = acc[k]     * inv + bp[k];
        float o1 = acc[k + 1] * inv + bp[k + 1];
        if (act == 1) {
            o0 = o0 > 0.f ? o0 : (__expf(o0) - 1.f);   // elu
            o1 = o1 > 0.f ? o1 : (__expf(o1) - 1.f);
        }
        short h0 = f2bf(o0), h1 = f2bf(o1);
        short l0 = f2bf(o0 - bf2f(h0)), l1 = f2bf(o1 - bf2f(h1));
        ((unsigned*)(ohi + ob))[k / 2] = pack2(h0, h1);
        ((unsigned*)(olo + ob))[k / 2] = pack2(l0, l1);
    }
}

extern "C" void kernel_launch(void* const* d_in, const int* in_sizes, int n_in,
                              void* d_out, int out_size, void* d_ws, size_t ws_size,
                              hipStream_t stream) {
    const float* x   = (const float*)d_in[0];
    const int*   ei  = (const int*)d_in[1];
    const float* W1  = (const float*)d_in[2];
    const float* as1 = (const float*)d_in[3];
    const float* ad1 = (const float*)d_in[4];
    const float* b1  = (const float*)d_in[5];
    const float* W2  = (const float*)d_in[6];
    const float* as2 = (const float*)d_in[7];
    const float* ad2 = (const float*)d_in[8];
    const float* b2  = (const float*)d_in[9];
    const float* W3  = (const float*)d_in[10];
    const float* as3 = (const float*)d_in[11];
    const float* ad3 = (const float*)d_in[12];
    const float* b3  = (const float*)d_in[13];
    const float* M1  = (const float*)d_in[14];
    const float* mb1 = (const float*)d_in[15];
    const float* M2  = (const float*)d_in[16];
    const float* mb2 = (const float*)d_in[17];
    const float* M3  = (const float*)d_in[18];
    const float* mb3 = (const float*)d_in[19];
    float* out = (float*)d_out;

    const int N = in_sizes[0] / IN_F;   // 50000
    const int E = in_sizes[1] / 2;      // 800000
    const int* src = ei;
    const int* dst = ei + E;

    char* ws = (char*)d_ws;
    auto alloc = [&](size_t bytes) { char* p = ws; ws += (bytes + 255) & ~(size_t)255; return p; };
    float* Hf  = (float*)alloc((size_t)N * CATF * 4);   // fp32 GEMM output (GAT layers)
    short* Ph  = (short*)alloc((size_t)N * CATF * 2);   // hi plane (GEMM input)
    short* Pl  = (short*)alloc((size_t)N * CATF * 2);   // lo plane
    float* al_s = (float*)alloc((size_t)N * HEADS * 4);
    float* al_d = (float*)alloc((size_t)N * HEADS * 4);
    int* cnt    = (int*)alloc((size_t)N * 4);
    int* pos    = (int*)alloc((size_t)N * 4);
    int* indptr = (int*)alloc((size_t)(N + 1) * 4);
    int* esrc   = (int*)alloc((size_t)(E + N) * 4);
    auto walloc = [&](int k, int n, short*& h, short*& l) {
        h = (short*)alloc((size_t)k * n * 2);
        l = (short*)alloc((size_t)k * n * 2);
    };
    short *W1h, *W1l, *W2h, *W2l, *W3h, *W3l, *M1h, *M1l, *M2h, *M2l, *M3h, *M3l;
    walloc(IN_F, CATF, W1h, W1l);
    walloc(CATF, CATF, W2h, W2l);
    walloc(CATF, OUT_F, W3h, W3l);
    walloc(OUT_F, 2 * HIDC, M1h, M1l);
    walloc(2 * HIDC, HIDC, M2h, M2l);
    walloc(HIDC, OUT_F, M3h, M3l);

    // ---- CSR build ----
    init_counts<<<(N + 255) / 256, 256, 0, stream>>>(cnt, N);
    count_dst<<<(E + 255) / 256, 256, 0, stream>>>(dst, E, cnt);
    scan_counts<<<1, 1024, 0, stream>>>(cnt, indptr, pos, N);
    scatter_edges<<<(E + N + 255) / 256, 256, 0, stream>>>(src, dst, E, N, pos, esrc);

    // ---- weight conversion + transpose ----
    auto convw = [&](const float* W, short* h, short* l, int K, int Nc) {
        conv_w_t<<<(K * Nc + 255) / 256, 256, 0, stream>>>(W, h, l, K, Nc);
    };
    convw(W1, W1h, W1l, IN_F, CATF);
    convw(W2, W2h, W2l, CATF, CATF);
    convw(W3, W3h, W3l, CATF, OUT_F);
    convw(M1, M1h, M1l, OUT_F, 2 * HIDC);
    convw(M2, M2h, M2l, 2 * HIDC, HIDC);
    convw(M3, M3h, M3l, HIDC, OUT_F);

    auto gemm_f = [&](const short* Ahp, const short* Alp, const short* Bhp, const short* Blp,
                      const float* bias, float* of, int M, int Nc, int K, int act) {
        dim3 grid(Nc / TN, (M + TM - 1) / TM);
        gemm_bt<1><<<grid, 256, 0, stream>>>(Ahp, Alp, Bhp, Blp, bias, nullptr, nullptr, of, M, Nc, K, act);
    };
    auto gemm_hl = [&](const short* Ahp, const short* Alp, const short* Bhp, const short* Blp,
                       const float* bias, short* oh, short* ol, int M, int Nc, int K, int act) {
        dim3 grid(Nc / TN, (M + TM - 1) / TM);
        gemm_bt<0><<<grid, 256, 0, stream>>>(Ahp, Alp, Bhp, Blp, bias, oh, ol, nullptr, M, Nc, K, act);
    };

    // ---- input conversion: x -> Ph/Pl [N,256] ----
    conv_split<<<((long)N * IN_F / 2 + 255) / 256, 256, 0, stream>>>(x, Ph, Pl, (long)N * IN_F / 2);

    // ---- GAT layer 1: Hf = (Ph,Pl)@W1 [N,512]; aggregate+ELU -> Ph/Pl ----
    gemm_f(Ph, Pl, W1h, W1l, nullptr, Hf, N, CATF, IN_F, 0);
    attn_coef_f<<<N, HEADS * 64, 0, stream>>>(Hf, as1, ad1, al_s, al_d, N, HEADS, HIDC);
    gat_aggregate_m<8, HEADS><<<(N + 3) / 4, 256, 0, stream>>>(Hf, al_s, al_d, indptr, esrc,
                                                               b1, Ph, Pl, N, 1);
    // ---- GAT layer 2 ----
    gemm_f(Ph, Pl, W2h, W2l, nullptr, Hf, N, CATF, CATF, 0);
    attn_coef_f<<<N, HEADS * 64, 0, stream>>>(Hf, as2, ad2, al_s, al_d, N, HEADS, HIDC);
    gat_aggregate_m<8, HEADS><<<(N + 3) / 4, 256, 0, stream>>>(Hf, al_s, al_d, indptr, esrc,
                                                               b2, Ph, Pl, N, 1);
    // ---- GAT layer 3 (1 head, C=256, no ELU) ----
    gemm_f(Ph, Pl, W3h, W3l, nullptr, Hf, N, OUT_F, CATF, 0);
    attn_coef_f<<<N, 64, 0, stream>>>(Hf, as3, ad3, al_s, al_d, N, 1, OUT_F);
    gat_aggregate_m<4, 1><<<(N + 3) / 4, 256, 0, stream>>>(Hf, al_s, al_d, indptr, esrc,
                                                           b3, Ph, Pl, N, 0);
    // ---- MLP ----
    short* Qh = (short*)Hf;                    // reuse Hf space for MLP planes
    short* Ql = Qh + (size_t)N * 2 * HIDC;
    short* Rh = Ph + (size_t)N * OUT_F;        // second halves of Ph/Pl (unused)
    short* Rl = Pl + (size_t)N * OUT_F;
    gemm_hl(Ph, Pl, M1h, M1l, mb1, Qh, Ql, N, 2 * HIDC, OUT_F, 1);    // relu, [N,256]
    gemm_hl(Qh, Ql, M2h, M2l, mb2, Rh, Rl, N, HIDC, 2 * HIDC, 1);     // relu, [N,128]
    {
        dim3 grid(OUT_F / TN, (N + TM - 1) / TM);
        gemm_bt<1><<<grid, 256, 0, stream>>>(Rh, Rl, M3h, M3l, mb3, nullptr, nullptr, out,
                                             N, OUT_F, HIDC, 0);
    }
}

// Round 4
// 1155.510 us; speedup vs baseline: 2.2558x; 1.2085x over previous
//
#include <hip/hip_runtime.h>
#include <cstdint>
#include <cstddef>

#define HEADS  4
#define HIDC   128
#define CATF   512
#define IN_F   256
#define OUT_F  256

typedef short bf16x8 __attribute__((ext_vector_type(8)));
typedef float f32x4  __attribute__((ext_vector_type(4)));
typedef _Float16 h16x8 __attribute__((ext_vector_type(8)));
typedef _Float16 h16x4 __attribute__((ext_vector_type(4)));

__device__ __forceinline__ short f2bf(float f) {
    unsigned u = __builtin_bit_cast(unsigned, f);
    u = u + 0x7fffu + ((u >> 16) & 1u);   // round-to-nearest-even
    return (short)(u >> 16);
}
__device__ __forceinline__ float bf2f(short s) {
    return __builtin_bit_cast(float, ((unsigned)(unsigned short)s) << 16);
}
__device__ __forceinline__ unsigned pack2(short a, short b) {
    return (unsigned)(unsigned short)a | ((unsigned)(unsigned short)b << 16);
}

__device__ __forceinline__ void async16(const void* g, void* l) {
    __builtin_amdgcn_global_load_lds((const __attribute__((address_space(1))) void*)g,
                                     (__attribute__((address_space(3))) void*)l, 16, 0, 0);
}

// ---------------- CSR build ----------------
__global__ void init_counts(int* cnt, int N) {
    int i = blockIdx.x * blockDim.x + threadIdx.x;
    if (i < N) cnt[i] = 1;  // self loop
}

__global__ void count_dst(const int* __restrict__ dst, int E, int* cnt) {
    int i = blockIdx.x * blockDim.x + threadIdx.x;
    if (i < E) atomicAdd(&cnt[dst[i]], 1);
}

__global__ void scan_counts(const int* __restrict__ cnt, int* indptr, int* pos, int N) {
    __shared__ int tmp[1024];
    __shared__ int carry;
    if (threadIdx.x == 0) carry = 0;
    __syncthreads();
    for (int base = 0; base < N; base += 1024) {
        int i = base + (int)threadIdx.x;
        int v = (i < N) ? cnt[i] : 0;
        tmp[threadIdx.x] = v;
        __syncthreads();
        for (int off = 1; off < 1024; off <<= 1) {
            int t = (threadIdx.x >= (unsigned)off) ? tmp[threadIdx.x - off] : 0;
            __syncthreads();
            tmp[threadIdx.x] += t;
            __syncthreads();
        }
        int excl = tmp[threadIdx.x] - v;
        if (i < N) { indptr[i] = carry + excl; pos[i] = carry + excl; }
        __syncthreads();
        if (threadIdx.x == 1023) carry += tmp[1023];
        __syncthreads();
    }
    if (threadIdx.x == 0) indptr[N] = carry;
}

__global__ void scatter_edges(const int* __restrict__ src, const int* __restrict__ dst,
                              int E, int N, int* pos, int* esrc) {
    int i = blockIdx.x * blockDim.x + threadIdx.x;
    int total = E + N;
    if (i >= total) return;
    int s, d;
    if (i < E) { s = src[i]; d = dst[i]; }
    else       { s = i - E;  d = s; }
    int p = atomicAdd(&pos[d], 1);
    esrc[p] = s;
}

// ---------------- fp32 -> (hi,lo) bf16 planes ----------------
__global__ void conv_split(const float* __restrict__ in, short* __restrict__ hi,
                           short* __restrict__ lo, long n2) {  // n2 = n/2
    long i = (long)blockIdx.x * blockDim.x + threadIdx.x;
    if (i >= n2) return;
    float2 v = ((const float2*)in)[i];
    short h0 = f2bf(v.x), h1 = f2bf(v.y);
    short l0 = f2bf(v.x - bf2f(h0)), l1 = f2bf(v.y - bf2f(h1));
    ((unsigned*)hi)[i] = pack2(h0, h1);
    ((unsigned*)lo)[i] = pack2(l0, l1);
}

// W[K,N] fp32 -> Bt_hi/Bt_lo [N,K] bf16 (transposed)
__global__ void conv_w_t(const float* __restrict__ W, short* __restrict__ hi,
                         short* __restrict__ lo, int K, int N) {
    int idx = blockIdx.x * blockDim.x + threadIdx.x;
    if (idx >= K * N) return;
    int n = idx / K, k = idx - n * K;
    float v = W[(size_t)k * N + n];
    short h = f2bf(v);
    hi[(size_t)n * K + k] = h;
    lo[(size_t)n * K + k] = f2bf(v - bf2f(h));
}

// ---------------- bf16x3 MFMA GEMM: C = A @ Bt^T ----------------
// MODE 0: out -> hi/lo bf16 planes;  MODE 1: out -> fp32;  MODE 2: out -> fp16.
#define TM 128
#define TN 128
#define TK 32
template <int MODE>
__global__ __launch_bounds__(256) void gemm_bt(
        const short* __restrict__ Ah, const short* __restrict__ Al,
        const short* __restrict__ Bh, const short* __restrict__ Bl,
        const float* __restrict__ bias,
        short* __restrict__ out_hi, short* __restrict__ out_lo, float* __restrict__ out_f,
        _Float16* __restrict__ out_h16,
        int M, int N, int K, int act) {
    __shared__ __align__(16) short sAh[TM * TK], sAl[TM * TK], sBh[TN * TK], sBl[TN * TK];
    int tid = threadIdx.x;
    int wave = tid >> 6, lane = tid & 63;
    int m0 = blockIdx.y * TM, n0 = blockIdx.x * TN;
    int wm = wave >> 1, wn = wave & 1;           // 2x2 waves, each 64x64
    int srow = lane >> 2;
    int skel = (lane & 3) * 8;
    int fr = lane & 15, quad = lane >> 4;

    f32x4 acc[4][4];
#pragma unroll
    for (int i = 0; i < 4; i++)
#pragma unroll
        for (int j = 0; j < 4; j++) acc[i][j] = (f32x4){0.f, 0.f, 0.f, 0.f};

    for (int k0 = 0; k0 < K; k0 += TK) {
        __syncthreads();
#pragma unroll
        for (int c = 0; c < 2; c++) {
            int chunk = wave * 2 + c;
            int r = chunk * 16 + srow;
            int gmA = m0 + r; if (gmA >= M) gmA = M - 1;
            int gnB = n0 + r;
            size_t aoff = (size_t)gmA * K + k0 + skel;
            size_t boff = (size_t)gnB * K + k0 + skel;
            int ldso = chunk * 512;
            async16(Ah + aoff, &sAh[ldso]);
            async16(Al + aoff, &sAl[ldso]);
            async16(Bh + boff, &sBh[ldso]);
            async16(Bl + boff, &sBl[ldso]);
        }
        __syncthreads();

        bf16x8 fah[4], fal[4], fbh[4], fbl[4];
#pragma unroll
        for (int i = 0; i < 4; i++) {
            int ra = (wm * 64 + i * 16 + fr) * TK + quad * 8;
            int rb = (wn * 64 + i * 16 + fr) * TK + quad * 8;
            fah[i] = *(const bf16x8*)&sAh[ra];
            fal[i] = *(const bf16x8*)&sAl[ra];
            fbh[i] = *(const bf16x8*)&sBh[rb];
            fbl[i] = *(const bf16x8*)&sBl[rb];
        }
#pragma unroll
        for (int i = 0; i < 4; i++)
#pragma unroll
            for (int j = 0; j < 4; j++) {
                acc[i][j] = __builtin_amdgcn_mfma_f32_16x16x32_bf16(fah[i], fbl[j], acc[i][j], 0, 0, 0);
                acc[i][j] = __builtin_amdgcn_mfma_f32_16x16x32_bf16(fal[i], fbh[j], acc[i][j], 0, 0, 0);
                acc[i][j] = __builtin_amdgcn_mfma_f32_16x16x32_bf16(fah[i], fbh[j], acc[i][j], 0, 0, 0);
            }
    }

#pragma unroll
    for (int i = 0; i < 4; i++)
#pragma unroll
        for (int r = 0; r < 4; r++) {
            int gm = m0 + wm * 64 + i * 16 + quad * 4 + r;
            if (gm >= M) continue;
#pragma unroll
            for (int j = 0; j < 4; j++) {
                int gn = n0 + wn * 64 + j * 16 + fr;
                float v = acc[i][j][r];
                if (bias) v += bias[gn];
                if (act == 1) v = fmaxf(v, 0.f);
                size_t o = (size_t)gm * N + gn;
                if (MODE == 0) {
                    short h = f2bf(v);
                    out_hi[o] = h;
                    out_lo[o] = f2bf(v - bf2f(h));
                } else if (MODE == 1) {
                    out_f[o] = v;
                } else {
                    out_h16[o] = (_Float16)v;
                }
            }
        }
}

// ---------------- attention coefficients (fp16 h) ----------------
__global__ void attn_coef_h(const _Float16* __restrict__ h, const float* __restrict__ a_src,
                            const float* __restrict__ a_dst, float* __restrict__ al_s,
                            float* __restrict__ al_d, int N, int H, int C) {
    int n = blockIdx.x;
    int w = threadIdx.x >> 6;
    int lane = threadIdx.x & 63;
    size_t base = ((size_t)n * H + w) * C;
    float ss = 0.f, sd = 0.f;
    for (int c = lane; c < C; c += 64) {
        float v = (float)h[base + c];
        ss += v * a_src[w * C + c];
        sd += v * a_dst[w * C + c];
    }
#pragma unroll
    for (int off = 32; off > 0; off >>= 1) {
        ss += __shfl_down(ss, off);
        sd += __shfl_down(sd, off);
    }
    if (lane == 0) {
        al_s[n * H + w] = ss;
        al_d[n * H + w] = sd;
    }
}

// ---------------- merged-head GAT aggregation (fp16 gather) ----------------
// one wave per node; lane owns CT consecutive halfs of the C_ALL = CT*64 row.
template <int CT, int H>
__global__ void gat_aggregate_m(const _Float16* __restrict__ h,
                                const float* __restrict__ al_s, const float* __restrict__ al_d,
                                const int* __restrict__ indptr, const int* __restrict__ esrc,
                                const float* __restrict__ bias,
                                short* __restrict__ ohi, short* __restrict__ olo,
                                int N, int act) {
    typedef _Float16 hvec __attribute__((ext_vector_type(CT)));
    const int C_ALL = CT * 64;
    int n = (blockIdx.x * blockDim.x + threadIdx.x) >> 6;
    int lane = threadIdx.x & 63;
    if (n >= N) return;
    int head = (lane * H) >> 6;
    float ald = al_d[n * H + head];
    float l = 0.f;
    float acc[CT];
#pragma unroll
    for (int k = 0; k < CT; k++) acc[k] = 0.f;

    int beg = indptr[n], end = indptr[n + 1];   // >=1 edge (self loop)
    int s = esrc[beg];
    float as = al_s[s * H + head];
    for (int idx = beg; idx < end; ++idx) {
        int s_cur = s;
        float as_cur = as;
        if (idx + 1 < end) {                    // prefetch next edge's scalars
            s = esrc[idx + 1];
            as = al_s[s * H + head];
        }
        float e = as_cur + ald;
        e = e > 0.f ? e : 0.2f * e;             // leaky_relu 0.2
        e = fminf(e, 60.f);
        float w = __expf(e);
        l += w;
        hvec v = *(const hvec*)(h + (size_t)s_cur * C_ALL + lane * CT);
#pragma unroll
        for (int k = 0; k < CT; k++) acc[k] += w * (float)v[k];
    }
    float inv = 1.f / (l + 1e-16f);
    size_t ob = (size_t)n * C_ALL + lane * CT;
    const float* bp = bias + lane * CT;
#pragma unroll
    for (int k = 0; k < CT; k += 2) {
        float o0 = acc[k]     * inv + bp[k];
        float o1 = acc[k + 1] * inv + bp[k + 1];
        if (act == 1) {
            o0 = o0 > 0.f ? o0 : (__expf(o0) - 1.f);   // elu
            o1 = o1 > 0.f ? o1 : (__expf(o1) - 1.f);
        }
        short h0 = f2bf(o0), h1 = f2bf(o1);
        short l0 = f2bf(o0 - bf2f(h0)), l1 = f2bf(o1 - bf2f(h1));
        ((unsigned*)(ohi + ob))[k / 2] = pack2(h0, h1);
        ((unsigned*)(olo + ob))[k / 2] = pack2(l0, l1);
    }
}

extern "C" void kernel_launch(void* const* d_in, const int* in_sizes, int n_in,
                              void* d_out, int out_size, void* d_ws, size_t ws_size,
                              hipStream_t stream) {
    const float* x   = (const float*)d_in[0];
    const int*   ei  = (const int*)d_in[1];
    const float* W1  = (const float*)d_in[2];
    const float* as1 = (const float*)d_in[3];
    const float* ad1 = (const float*)d_in[4];
    const float* b1  = (const float*)d_in[5];
    const float* W2  = (const float*)d_in[6];
    const float* as2 = (const float*)d_in[7];
    const float* ad2 = (const float*)d_in[8];
    const float* b2  = (const float*)d_in[9];
    const float* W3  = (const float*)d_in[10];
    const float* as3 = (const float*)d_in[11];
    const float* ad3 = (const float*)d_in[12];
    const float* b3  = (const float*)d_in[13];
    const float* M1  = (const float*)d_in[14];
    const float* mb1 = (const float*)d_in[15];
    const float* M2  = (const float*)d_in[16];
    const float* mb2 = (const float*)d_in[17];
    const float* M3  = (const float*)d_in[18];
    const float* mb3 = (const float*)d_in[19];
    float* out = (float*)d_out;

    const int N = in_sizes[0] / IN_F;   // 50000
    const int E = in_sizes[1] / 2;      // 800000
    const int* src = ei;
    const int* dst = ei + E;

    char* ws = (char*)d_ws;
    auto alloc = [&](size_t bytes) { char* p = ws; ws += (bytes + 255) & ~(size_t)255; return p; };
    _Float16* H16 = (_Float16*)alloc((size_t)N * CATF * 2);  // fp16 GEMM output (GAT layers)
    short* Ph  = (short*)alloc((size_t)N * CATF * 2);        // hi plane (GEMM input)
    short* Pl  = (short*)alloc((size_t)N * CATF * 2);        // lo plane
    float* al_s = (float*)alloc((size_t)N * HEADS * 4);
    float* al_d = (float*)alloc((size_t)N * HEADS * 4);
    int* cnt    = (int*)alloc((size_t)N * 4);
    int* pos    = (int*)alloc((size_t)N * 4);
    int* indptr = (int*)alloc((size_t)(N + 1) * 4);
    int* esrc   = (int*)alloc((size_t)(E + N) * 4);
    auto walloc = [&](int k, int n, short*& h, short*& l) {
        h = (short*)alloc((size_t)k * n * 2);
        l = (short*)alloc((size_t)k * n * 2);
    };
    short *W1h, *W1l, *W2h, *W2l, *W3h, *W3l, *M1h, *M1l, *M2h, *M2l, *M3h, *M3l;
    walloc(IN_F, CATF, W1h, W1l);
    walloc(CATF, CATF, W2h, W2l);
    walloc(CATF, OUT_F, W3h, W3l);
    walloc(OUT_F, 2 * HIDC, M1h, M1l);
    walloc(2 * HIDC, HIDC, M2h, M2l);
    walloc(HIDC, OUT_F, M3h, M3l);

    // ---- CSR build ----
    init_counts<<<(N + 255) / 256, 256, 0, stream>>>(cnt, N);
    count_dst<<<(E + 255) / 256, 256, 0, stream>>>(dst, E, cnt);
    scan_counts<<<1, 1024, 0, stream>>>(cnt, indptr, pos, N);
    scatter_edges<<<(E + N + 255) / 256, 256, 0, stream>>>(src, dst, E, N, pos, esrc);

    // ---- weight conversion + transpose ----
    auto convw = [&](const float* W, short* h, short* l, int K, int Nc) {
        conv_w_t<<<(K * Nc + 255) / 256, 256, 0, stream>>>(W, h, l, K, Nc);
    };
    convw(W1, W1h, W1l, IN_F, CATF);
    convw(W2, W2h, W2l, CATF, CATF);
    convw(W3, W3h, W3l, CATF, OUT_F);
    convw(M1, M1h, M1l, OUT_F, 2 * HIDC);
    convw(M2, M2h, M2l, 2 * HIDC, HIDC);
    convw(M3, M3h, M3l, HIDC, OUT_F);

    auto gemm_h16 = [&](const short* Ahp, const short* Alp, const short* Bhp, const short* Blp,
                        const float* bias, _Float16* oh, int M, int Nc, int K, int act) {
        dim3 grid(Nc / TN, (M + TM - 1) / TM);
        gemm_bt<2><<<grid, 256, 0, stream>>>(Ahp, Alp, Bhp, Blp, bias, nullptr, nullptr, nullptr,
                                             oh, M, Nc, K, act);
    };
    auto gemm_hl = [&](const short* Ahp, const short* Alp, const short* Bhp, const short* Blp,
                       const float* bias, short* oh, short* ol, int M, int Nc, int K, int act) {
        dim3 grid(Nc / TN, (M + TM - 1) / TM);
        gemm_bt<0><<<grid, 256, 0, stream>>>(Ahp, Alp, Bhp, Blp, bias, oh, ol, nullptr,
                                             nullptr, M, Nc, K, act);
    };

    // ---- input conversion: x -> Ph/Pl [N,256] ----
    conv_split<<<((long)N * IN_F / 2 + 255) / 256, 256, 0, stream>>>(x, Ph, Pl, (long)N * IN_F / 2);

    // ---- GAT layer 1: H16 = (Ph,Pl)@W1 [N,512]; aggregate+ELU -> Ph/Pl ----
    gemm_h16(Ph, Pl, W1h, W1l, nullptr, H16, N, CATF, IN_F, 0);
    attn_coef_h<<<N, HEADS * 64, 0, stream>>>(H16, as1, ad1, al_s, al_d, N, HEADS, HIDC);
    gat_aggregate_m<8, HEADS><<<(N + 3) / 4, 256, 0, stream>>>(H16, al_s, al_d, indptr, esrc,
                                                               b1, Ph, Pl, N, 1);
    // ---- GAT layer 2 ----
    gemm_h16(Ph, Pl, W2h, W2l, nullptr, H16, N, CATF, CATF, 0);
    attn_coef_h<<<N, HEADS * 64, 0, stream>>>(H16, as2, ad2, al_s, al_d, N, HEADS, HIDC);
    gat_aggregate_m<8, HEADS><<<(N + 3) / 4, 256, 0, stream>>>(H16, al_s, al_d, indptr, esrc,
                                                               b2, Ph, Pl, N, 1);
    // ---- GAT layer 3 (1 head, C=256, no ELU) ----
    gemm_h16(Ph, Pl, W3h, W3l, nullptr, H16, N, OUT_F, CATF, 0);
    attn_coef_h<<<N, 64, 0, stream>>>(H16, as3, ad3, al_s, al_d, N, 1, OUT_F);
    gat_aggregate_m<4, 1><<<(N + 3) / 4, 256, 0, stream>>>(H16, al_s, al_d, indptr, esrc,
                                                           b3, Ph, Pl, N, 0);
    // ---- MLP ----
    short* Qh = (short*)H16;                   // reuse H16 space for MLP planes
    short* Ql = Qh + (size_t)N * 2 * HIDC;
    short* Rh = Ph + (size_t)N * OUT_F;        // second halves of Ph/Pl (unused)
    short* Rl = Pl + (size_t)N * OUT_F;
    gemm_hl(Ph, Pl, M1h, M1l, mb1, Qh, Ql, N, 2 * HIDC, OUT_F, 1);    // relu, [N,256]
    gemm_hl(Qh, Ql, M2h, M2l, mb2, Rh, Rl, N, HIDC, 2 * HIDC, 1);     // relu, [N,128]
    {
        dim3 grid(OUT_F / TN, (N + TM - 1) / TM);
        gemm_bt<1><<<grid, 256, 0, stream>>>(Rh, Rl, M3h, M3l, mb3, nullptr, nullptr, out,
                                             nullptr, N, OUT_F, HIDC, 0);
    }
}

// Round 5
// 1050.799 us; speedup vs baseline: 2.4805x; 1.0996x over previous
//
#include <hip/hip_runtime.h>
#include <cstdint>
#include <cstddef>

#define HEADS  4
#define HIDC   128
#define CATF   512
#define IN_F   256
#define OUT_F  256

typedef short bf16x8 __attribute__((ext_vector_type(8)));
typedef float f32x4  __attribute__((ext_vector_type(4)));

__device__ __forceinline__ short f2bf(float f) {
    unsigned u = __builtin_bit_cast(unsigned, f);
    u = u + 0x7fffu + ((u >> 16) & 1u);   // round-to-nearest-even
    return (short)(u >> 16);
}
__device__ __forceinline__ float bf2f(short s) {
    return __builtin_bit_cast(float, ((unsigned)(unsigned short)s) << 16);
}
__device__ __forceinline__ unsigned pack2(short a, short b) {
    return (unsigned)(unsigned short)a | ((unsigned)(unsigned short)b << 16);
}

__device__ __forceinline__ void async16(const void* g, void* l) {
    __builtin_amdgcn_global_load_lds((const __attribute__((address_space(1))) void*)g,
                                     (__attribute__((address_space(3))) void*)l, 16, 0, 0);
}

// ---------------- CSR build ----------------
__global__ void init_counts(int* cnt, int N) {
    int i = blockIdx.x * blockDim.x + threadIdx.x;
    if (i < N) cnt[i] = 1;  // self loop
}

__global__ void count_dst(const int* __restrict__ dst, int E, int* cnt) {
    int i = blockIdx.x * blockDim.x + threadIdx.x;
    if (i < E) atomicAdd(&cnt[dst[i]], 1);
}

// hierarchical scan: partial per-block exclusive scan + block sums
__global__ void scan_partial(const int* __restrict__ cnt, int* excl, int* bsum, int N) {
    __shared__ int tmp[256];
    int i = blockIdx.x * 256 + threadIdx.x;
    int v = (i < N) ? cnt[i] : 0;
    tmp[threadIdx.x] = v;
    __syncthreads();
    for (int off = 1; off < 256; off <<= 1) {
        int t = ((int)threadIdx.x >= off) ? tmp[threadIdx.x - off] : 0;
        __syncthreads();
        tmp[threadIdx.x] += t;
        __syncthreads();
    }
    if (i < N) excl[i] = tmp[threadIdx.x] - v;
    if (threadIdx.x == 255) bsum[blockIdx.x] = tmp[255];
}

__global__ void scan_bsums(int* bsum, int nb) {   // single block, nb <= 256
    __shared__ int tmp[256];
    int v = ((int)threadIdx.x < nb) ? bsum[threadIdx.x] : 0;
    tmp[threadIdx.x] = v;
    __syncthreads();
    for (int off = 1; off < 256; off <<= 1) {
        int t = ((int)threadIdx.x >= off) ? tmp[threadIdx.x - off] : 0;
        __syncthreads();
        tmp[threadIdx.x] += t;
        __syncthreads();
    }
    if ((int)threadIdx.x < nb) bsum[threadIdx.x] = tmp[threadIdx.x] - v;
}

__global__ void add_carry(int* indptr, int* pos, const int* __restrict__ bsum, int N, int total) {
    int i = blockIdx.x * blockDim.x + threadIdx.x;
    if (i < N) {
        int v = indptr[i] + bsum[i >> 8];
        indptr[i] = v;
        pos[i] = v;
    }
    if (i == 0) indptr[N] = total;
}

__global__ void scatter_edges(const int* __restrict__ src, const int* __restrict__ dst,
                              int E, int N, int* pos, int* esrc) {
    int i = blockIdx.x * blockDim.x + threadIdx.x;
    int total = E + N;
    if (i >= total) return;
    int s, d;
    if (i < E) { s = src[i]; d = dst[i]; }
    else       { s = i - E;  d = s; }
    int p = atomicAdd(&pos[d], 1);
    esrc[p] = s;
}

// ---------------- fp32 -> (hi,lo) bf16 planes ----------------
__global__ void conv_split(const float* __restrict__ in, short* __restrict__ hi,
                           short* __restrict__ lo, long n2) {  // n2 = n/2
    long i = (long)blockIdx.x * blockDim.x + threadIdx.x;
    if (i >= n2) return;
    float2 v = ((const float2*)in)[i];
    short h0 = f2bf(v.x), h1 = f2bf(v.y);
    short l0 = f2bf(v.x - bf2f(h0)), l1 = f2bf(v.y - bf2f(h1));
    ((unsigned*)hi)[i] = pack2(h0, h1);
    ((unsigned*)lo)[i] = pack2(l0, l1);
}

// W[K,N] fp32 -> Bt_hi/Bt_lo [N,K] bf16 (transposed)
__global__ void conv_w_t(const float* __restrict__ W, short* __restrict__ hi,
                         short* __restrict__ lo, int K, int N) {
    int idx = blockIdx.x * blockDim.x + threadIdx.x;
    if (idx >= K * N) return;
    int n = idx / K, k = idx - n * K;
    float v = W[(size_t)k * N + n];
    short h = f2bf(v);
    hi[(size_t)n * K + k] = h;
    lo[(size_t)n * K + k] = f2bf(v - bf2f(h));
}

// ---------------- bf16x3 MFMA GEMM: C = A @ Bt^T ----------------
// MODE 0: out -> hi/lo bf16 planes;  MODE 1: out -> fp32;  MODE 2: out -> fp16.
#define TM 128
#define TN 128
#define TK 32
template <int MODE>
__global__ __launch_bounds__(256) void gemm_bt(
        const short* __restrict__ Ah, const short* __restrict__ Al,
        const short* __restrict__ Bh, const short* __restrict__ Bl,
        const float* __restrict__ bias,
        short* __restrict__ out_hi, short* __restrict__ out_lo, float* __restrict__ out_f,
        _Float16* __restrict__ out_h16,
        int M, int N, int K, int act) {
    __shared__ __align__(16) short sAh[TM * TK], sAl[TM * TK], sBh[TN * TK], sBl[TN * TK];
    int tid = threadIdx.x;
    int wave = tid >> 6, lane = tid & 63;
    int m0 = blockIdx.y * TM, n0 = blockIdx.x * TN;
    int wm = wave >> 1, wn = wave & 1;           // 2x2 waves, each 64x64
    int srow = lane >> 2;
    int skel = (lane & 3) * 8;
    int fr = lane & 15, quad = lane >> 4;

    f32x4 acc[4][4];
#pragma unroll
    for (int i = 0; i < 4; i++)
#pragma unroll
        for (int j = 0; j < 4; j++) acc[i][j] = (f32x4){0.f, 0.f, 0.f, 0.f};

    for (int k0 = 0; k0 < K; k0 += TK) {
        __syncthreads();
#pragma unroll
        for (int c = 0; c < 2; c++) {
            int chunk = wave * 2 + c;
            int r = chunk * 16 + srow;
            int gmA = m0 + r; if (gmA >= M) gmA = M - 1;
            int gnB = n0 + r;
            size_t aoff = (size_t)gmA * K + k0 + skel;
            size_t boff = (size_t)gnB * K + k0 + skel;
            int ldso = chunk * 512;
            async16(Ah + aoff, &sAh[ldso]);
            async16(Al + aoff, &sAl[ldso]);
            async16(Bh + boff, &sBh[ldso]);
            async16(Bl + boff, &sBl[ldso]);
        }
        __syncthreads();

        bf16x8 fah[4], fal[4], fbh[4], fbl[4];
#pragma unroll
        for (int i = 0; i < 4; i++) {
            int ra = (wm * 64 + i * 16 + fr) * TK + quad * 8;
            int rb = (wn * 64 + i * 16 + fr) * TK + quad * 8;
            fah[i] = *(const bf16x8*)&sAh[ra];
            fal[i] = *(const bf16x8*)&sAl[ra];
            fbh[i] = *(const bf16x8*)&sBh[rb];
            fbl[i] = *(const bf16x8*)&sBl[rb];
        }
#pragma unroll
        for (int i = 0; i < 4; i++)
#pragma unroll
            for (int j = 0; j < 4; j++) {
                acc[i][j] = __builtin_amdgcn_mfma_f32_16x16x32_bf16(fah[i], fbl[j], acc[i][j], 0, 0, 0);
                acc[i][j] = __builtin_amdgcn_mfma_f32_16x16x32_bf16(fal[i], fbh[j], acc[i][j], 0, 0, 0);
                acc[i][j] = __builtin_amdgcn_mfma_f32_16x16x32_bf16(fah[i], fbh[j], acc[i][j], 0, 0, 0);
            }
    }

#pragma unroll
    for (int i = 0; i < 4; i++)
#pragma unroll
        for (int r = 0; r < 4; r++) {
            int gm = m0 + wm * 64 + i * 16 + quad * 4 + r;
            if (gm >= M) continue;
#pragma unroll
            for (int j = 0; j < 4; j++) {
                int gn = n0 + wn * 64 + j * 16 + fr;
                float v = acc[i][j][r];
                if (bias) v += bias[gn];
                if (act == 1) v = fmaxf(v, 0.f);
                size_t o = (size_t)gm * N + gn;
                if (MODE == 0) {
                    short h = f2bf(v);
                    out_hi[o] = h;
                    out_lo[o] = f2bf(v - bf2f(h));
                } else if (MODE == 1) {
                    out_f[o] = v;
                } else {
                    out_h16[o] = (_Float16)v;
                }
            }
        }
}

// ---------------- attention coefficients (fp16 h) ----------------
__global__ void attn_coef_h(const _Float16* __restrict__ h, const float* __restrict__ a_src,
                            const float* __restrict__ a_dst, float* __restrict__ al_s,
                            float* __restrict__ al_d, int N, int H, int C) {
    int n = blockIdx.x;
    int w = threadIdx.x >> 6;
    int lane = threadIdx.x & 63;
    size_t base = ((size_t)n * H + w) * C;
    float ss = 0.f, sd = 0.f;
    for (int c = lane; c < C; c += 64) {
        float v = (float)h[base + c];
        ss += v * a_src[w * C + c];
        sd += v * a_dst[w * C + c];
    }
#pragma unroll
    for (int off = 32; off > 0; off >>= 1) {
        ss += __shfl_down(ss, off);
        sd += __shfl_down(sd, off);
    }
    if (lane == 0) {
        al_s[n * H + w] = ss;
        al_d[n * H + w] = sd;
    }
}

// ---------------- edge weights + denominators ----------------
// one wave per node; lane = slot*H + head (SLOTS = 64/H edge slots).
template <int H>
__global__ void edge_weights(const float* __restrict__ al_s, const float* __restrict__ al_d,
                             const int* __restrict__ indptr, const int* __restrict__ esrc,
                             float* __restrict__ wgt, float* __restrict__ denom, int N) {
    const int SLOTS = 64 / H;
    int n = (blockIdx.x * blockDim.x + threadIdx.x) >> 6;
    int lane = threadIdx.x & 63;
    if (n >= N) return;
    int head = lane & (H - 1);
    int slot = lane / H;
    float ald = al_d[n * H + head];
    float dsum = 0.f;
    int beg = indptr[n], end = indptr[n + 1];
    for (int base = beg; base < end; base += SLOTS) {
        int idx = base + slot;
        if (idx < end) {
            int s = esrc[idx];
            float e = al_s[s * H + head] + ald;
            e = e > 0.f ? e : 0.2f * e;          // leaky_relu 0.2
            e = fminf(e, 60.f);
            float w = __expf(e);
            wgt[(size_t)idx * H + head] = w;
            dsum += w;
        }
    }
#pragma unroll
    for (int off = H; off < 64; off <<= 1) dsum += __shfl_xor(dsum, off);
    if (lane < H) denom[n * H + lane] = dsum;
}

// ---------------- weighted-gather aggregation (2-edge unrolled) ----------------
// one wave per node; lane owns CT consecutive halfs of the C_ALL = CT*64 row.
template <int CT, int H>
__global__ void gat_aggregate_w(const _Float16* __restrict__ h,
                                const float* __restrict__ wgt, const float* __restrict__ denom,
                                const int* __restrict__ indptr, const int* __restrict__ esrc,
                                const float* __restrict__ bias,
                                short* __restrict__ ohi, short* __restrict__ olo,
                                int N, int act) {
    typedef _Float16 hvec __attribute__((ext_vector_type(CT)));
    const int C_ALL = CT * 64;
    int n = (blockIdx.x * blockDim.x + threadIdx.x) >> 6;
    int lane = threadIdx.x & 63;
    if (n >= N) return;
    int head = (lane * H) >> 6;
    float acc[CT];
#pragma unroll
    for (int k = 0; k < CT; k++) acc[k] = 0.f;

    int beg = indptr[n], end = indptr[n + 1];   // >=1 edge (self loop)
    int idx = beg;
    for (; idx + 2 <= end; idx += 2) {
        int s0 = esrc[idx], s1 = esrc[idx + 1];
        float w0 = wgt[(size_t)idx * H + head];
        float w1 = wgt[(size_t)(idx + 1) * H + head];
        hvec v0 = *(const hvec*)(h + (size_t)s0 * C_ALL + lane * CT);
        hvec v1 = *(const hvec*)(h + (size_t)s1 * C_ALL + lane * CT);
#pragma unroll
        for (int k = 0; k < CT; k++) acc[k] += w0 * (float)v0[k];
#pragma unroll
        for (int k = 0; k < CT; k++) acc[k] += w1 * (float)v1[k];
    }
    if (idx < end) {
        int s0 = esrc[idx];
        float w0 = wgt[(size_t)idx * H + head];
        hvec v0 = *(const hvec*)(h + (size_t)s0 * C_ALL + lane * CT);
#pragma unroll
        for (int k = 0; k < CT; k++) acc[k] += w0 * (float)v0[k];
    }
    float inv = 1.f / (denom[n * H + head] + 1e-16f);
    size_t ob = (size_t)n * C_ALL + lane * CT;
    const float* bp = bias + lane * CT;
#pragma unroll
    for (int k = 0; k < CT; k += 2) {
        float o0 = acc[k]     * inv + bp[k];
        float o1 = acc[k + 1] * inv + bp[k + 1];
        if (act == 1) {
            o0 = o0 > 0.f ? o0 : (__expf(o0) - 1.f);   // elu
            o1 = o1 > 0.f ? o1 : (__expf(o1) - 1.f);
        }
        short h0 = f2bf(o0), h1 = f2bf(o1);
        short l0 = f2bf(o0 - bf2f(h0)), l1 = f2bf(o1 - bf2f(h1));
        ((unsigned*)(ohi + ob))[k / 2] = pack2(h0, h1);
        ((unsigned*)(olo + ob))[k / 2] = pack2(l0, l1);
    }
}

extern "C" void kernel_launch(void* const* d_in, const int* in_sizes, int n_in,
                              void* d_out, int out_size, void* d_ws, size_t ws_size,
                              hipStream_t stream) {
    const float* x   = (const float*)d_in[0];
    const int*   ei  = (const int*)d_in[1];
    const float* W1  = (const float*)d_in[2];
    const float* as1 = (const float*)d_in[3];
    const float* ad1 = (const float*)d_in[4];
    const float* b1  = (const float*)d_in[5];
    const float* W2  = (const float*)d_in[6];
    const float* as2 = (const float*)d_in[7];
    const float* ad2 = (const float*)d_in[8];
    const float* b2  = (const float*)d_in[9];
    const float* W3  = (const float*)d_in[10];
    const float* as3 = (const float*)d_in[11];
    const float* ad3 = (const float*)d_in[12];
    const float* b3  = (const float*)d_in[13];
    const float* M1  = (const float*)d_in[14];
    const float* mb1 = (const float*)d_in[15];
    const float* M2  = (const float*)d_in[16];
    const float* mb2 = (const float*)d_in[17];
    const float* M3  = (const float*)d_in[18];
    const float* mb3 = (const float*)d_in[19];
    float* out = (float*)d_out;

    const int N = in_sizes[0] / IN_F;   // 50000
    const int E = in_sizes[1] / 2;      // 800000
    const int* src = ei;
    const int* dst = ei + E;

    char* ws = (char*)d_ws;
    auto alloc = [&](size_t bytes) { char* p = ws; ws += (bytes + 255) & ~(size_t)255; return p; };
    _Float16* H16 = (_Float16*)alloc((size_t)N * CATF * 2);  // fp16 GEMM output (GAT layers)
    short* Ph  = (short*)alloc((size_t)N * CATF * 2);        // hi plane (GEMM input)
    short* Pl  = (short*)alloc((size_t)N * CATF * 2);        // lo plane
    float* al_s = (float*)alloc((size_t)N * HEADS * 4);
    float* al_d = (float*)alloc((size_t)N * HEADS * 4);
    float* wgt  = (float*)alloc((size_t)(E + N) * HEADS * 4);
    float* denom = (float*)alloc((size_t)N * HEADS * 4);
    int* cnt    = (int*)alloc((size_t)N * 4);
    int* pos    = (int*)alloc((size_t)N * 4);
    int* indptr = (int*)alloc((size_t)(N + 1) * 4);
    int* esrc   = (int*)alloc((size_t)(E + N) * 4);
    int* bsum   = (int*)alloc(256 * 4);
    auto walloc = [&](int k, int n, short*& h, short*& l) {
        h = (short*)alloc((size_t)k * n * 2);
        l = (short*)alloc((size_t)k * n * 2);
    };
    short *W1h, *W1l, *W2h, *W2l, *W3h, *W3l, *M1h, *M1l, *M2h, *M2l, *M3h, *M3l;
    walloc(IN_F, CATF, W1h, W1l);
    walloc(CATF, CATF, W2h, W2l);
    walloc(CATF, OUT_F, W3h, W3l);
    walloc(OUT_F, 2 * HIDC, M1h, M1l);
    walloc(2 * HIDC, HIDC, M2h, M2l);
    walloc(HIDC, OUT_F, M3h, M3l);

    // ---- CSR build ----
    const int nb = (N + 255) / 256;   // 196
    init_counts<<<(N + 255) / 256, 256, 0, stream>>>(cnt, N);
    count_dst<<<(E + 255) / 256, 256, 0, stream>>>(dst, E, cnt);
    scan_partial<<<nb, 256, 0, stream>>>(cnt, indptr, bsum, N);
    scan_bsums<<<1, 256, 0, stream>>>(bsum, nb);
    add_carry<<<nb, 256, 0, stream>>>(indptr, pos, bsum, N, E + N);
    scatter_edges<<<(E + N + 255) / 256, 256, 0, stream>>>(src, dst, E, N, pos, esrc);

    // ---- weight conversion + transpose ----
    auto convw = [&](const float* W, short* h, short* l, int K, int Nc) {
        conv_w_t<<<(K * Nc + 255) / 256, 256, 0, stream>>>(W, h, l, K, Nc);
    };
    convw(W1, W1h, W1l, IN_F, CATF);
    convw(W2, W2h, W2l, CATF, CATF);
    convw(W3, W3h, W3l, CATF, OUT_F);
    convw(M1, M1h, M1l, OUT_F, 2 * HIDC);
    convw(M2, M2h, M2l, 2 * HIDC, HIDC);
    convw(M3, M3h, M3l, HIDC, OUT_F);

    auto gemm_h16 = [&](const short* Ahp, const short* Alp, const short* Bhp, const short* Blp,
                        const float* bias, _Float16* oh, int M, int Nc, int K, int act) {
        dim3 grid(Nc / TN, (M + TM - 1) / TM);
        gemm_bt<2><<<grid, 256, 0, stream>>>(Ahp, Alp, Bhp, Blp, bias, nullptr, nullptr, nullptr,
                                             oh, M, Nc, K, act);
    };
    auto gemm_hl = [&](const short* Ahp, const short* Alp, const short* Bhp, const short* Blp,
                       const float* bias, short* oh, short* ol, int M, int Nc, int K, int act) {
        dim3 grid(Nc / TN, (M + TM - 1) / TM);
        gemm_bt<0><<<grid, 256, 0, stream>>>(Ahp, Alp, Bhp, Blp, bias, oh, ol, nullptr,
                                             nullptr, M, Nc, K, act);
    };

    const int gwav = (N + 3) / 4;   // blocks of 4 waves, one wave per node

    // ---- input conversion: x -> Ph/Pl [N,256] ----
    conv_split<<<((long)N * IN_F / 2 + 255) / 256, 256, 0, stream>>>(x, Ph, Pl, (long)N * IN_F / 2);

    // ---- GAT layer 1 ----
    gemm_h16(Ph, Pl, W1h, W1l, nullptr, H16, N, CATF, IN_F, 0);
    attn_coef_h<<<N, HEADS * 64, 0, stream>>>(H16, as1, ad1, al_s, al_d, N, HEADS, HIDC);
    edge_weights<HEADS><<<gwav, 256, 0, stream>>>(al_s, al_d, indptr, esrc, wgt, denom, N);
    gat_aggregate_w<8, HEADS><<<gwav, 256, 0, stream>>>(H16, wgt, denom, indptr, esrc,
                                                        b1, Ph, Pl, N, 1);
    // ---- GAT layer 2 ----
    gemm_h16(Ph, Pl, W2h, W2l, nullptr, H16, N, CATF, CATF, 0);
    attn_coef_h<<<N, HEADS * 64, 0, stream>>>(H16, as2, ad2, al_s, al_d, N, HEADS, HIDC);
    edge_weights<HEADS><<<gwav, 256, 0, stream>>>(al_s, al_d, indptr, esrc, wgt, denom, N);
    gat_aggregate_w<8, HEADS><<<gwav, 256, 0, stream>>>(H16, wgt, denom, indptr, esrc,
                                                        b2, Ph, Pl, N, 1);
    // ---- GAT layer 3 (1 head, C=256, no ELU) ----
    gemm_h16(Ph, Pl, W3h, W3l, nullptr, H16, N, OUT_F, CATF, 0);
    attn_coef_h<<<N, 64, 0, stream>>>(H16, as3, ad3, al_s, al_d, N, 1, OUT_F);
    edge_weights<1><<<gwav, 256, 0, stream>>>(al_s, al_d, indptr, esrc, wgt, denom, N);
    gat_aggregate_w<4, 1><<<gwav, 256, 0, stream>>>(H16, wgt, denom, indptr, esrc,
                                                    b3, Ph, Pl, N, 0);
    // ---- MLP ----
    short* Qh = (short*)H16;                   // reuse H16 space for MLP planes
    short* Ql = Qh + (size_t)N * 2 * HIDC;
    short* Rh = Ph + (size_t)N * OUT_F;        // second halves of Ph/Pl (unused)
    short* Rl = Pl + (size_t)N * OUT_F;
    gemm_hl(Ph, Pl, M1h, M1l, mb1, Qh, Ql, N, 2 * HIDC, OUT_F, 1);    // relu, [N,256]
    gemm_hl(Qh, Ql, M2h, M2l, mb2, Rh, Rl, N, HIDC, 2 * HIDC, 1);     // relu, [N,128]
    {
        dim3 grid(OUT_F / TN, (N + TM - 1) / TM);
        gemm_bt<1><<<grid, 256, 0, stream>>>(Rh, Rl, M3h, M3l, mb3, nullptr, nullptr, out,
                                             nullptr, N, OUT_F, HIDC, 0);
    }
}

// Round 6
// 946.700 us; speedup vs baseline: 2.7533x; 1.1100x over previous
//
#include <hip/hip_runtime.h>
#include <cstdint>
#include <cstddef>

#define HEADS  4
#define HIDC   128
#define CATF   512
#define IN_F   256
#define OUT_F  256

typedef _Float16 f16x8 __attribute__((ext_vector_type(8)));
typedef _Float16 f16x4 __attribute__((ext_vector_type(4)));
typedef float f32x4  __attribute__((ext_vector_type(4)));

__device__ __forceinline__ void async16(const void* g, void* l) {
    __builtin_amdgcn_global_load_lds((const __attribute__((address_space(1))) void*)g,
                                     (__attribute__((address_space(3))) void*)l, 16, 0, 0);
}

// ---------------- CSR build ----------------
__global__ void init_counts(int* cnt, int N) {
    int i = blockIdx.x * blockDim.x + threadIdx.x;
    if (i < N) cnt[i] = 1;  // self loop
}

__global__ void count_dst(const int* __restrict__ dst, int E, int* cnt) {
    int i = blockIdx.x * blockDim.x + threadIdx.x;
    if (i < E) atomicAdd(&cnt[dst[i]], 1);
}

// hierarchical scan: partial per-block exclusive scan + block sums
__global__ void scan_partial(const int* __restrict__ cnt, int* excl, int* bsum, int N) {
    __shared__ int tmp[256];
    int i = blockIdx.x * 256 + threadIdx.x;
    int v = (i < N) ? cnt[i] : 0;
    tmp[threadIdx.x] = v;
    __syncthreads();
    for (int off = 1; off < 256; off <<= 1) {
        int t = ((int)threadIdx.x >= off) ? tmp[threadIdx.x - off] : 0;
        __syncthreads();
        tmp[threadIdx.x] += t;
        __syncthreads();
    }
    if (i < N) excl[i] = tmp[threadIdx.x] - v;
    if (threadIdx.x == 255) bsum[blockIdx.x] = tmp[255];
}

__global__ void scan_bsums(int* bsum, int nb) {   // single block, nb <= 256
    __shared__ int tmp[256];
    int v = ((int)threadIdx.x < nb) ? bsum[threadIdx.x] : 0;
    tmp[threadIdx.x] = v;
    __syncthreads();
    for (int off = 1; off < 256; off <<= 1) {
        int t = ((int)threadIdx.x >= off) ? tmp[threadIdx.x - off] : 0;
        __syncthreads();
        tmp[threadIdx.x] += t;
        __syncthreads();
    }
    if ((int)threadIdx.x < nb) bsum[threadIdx.x] = tmp[threadIdx.x] - v;
}

__global__ void add_carry(int* indptr, int* pos, const int* __restrict__ bsum, int N, int total) {
    int i = blockIdx.x * blockDim.x + threadIdx.x;
    if (i < N) {
        int v = indptr[i] + bsum[i >> 8];
        indptr[i] = v;
        pos[i] = v;
    }
    if (i == 0) indptr[N] = total;
}

__global__ void scatter_edges(const int* __restrict__ src, const int* __restrict__ dst,
                              int E, int N, int* pos, int* esrc) {
    int i = blockIdx.x * blockDim.x + threadIdx.x;
    int total = E + N;
    if (i >= total) return;
    int s, d;
    if (i < E) { s = src[i]; d = dst[i]; }
    else       { s = i - E;  d = s; }
    int p = atomicAdd(&pos[d], 1);
    esrc[p] = s;
}

// ---------------- fp32 -> fp16 ----------------
__global__ void conv_h16(const float* __restrict__ in, _Float16* __restrict__ out, long n4) {
    long i = (long)blockIdx.x * blockDim.x + threadIdx.x;
    if (i >= n4) return;
    float4 v = ((const float4*)in)[i];
    f16x4 o = { (_Float16)v.x, (_Float16)v.y, (_Float16)v.z, (_Float16)v.w };
    ((f16x4*)out)[i] = o;
}

// W[K,N] fp32 -> Wt_hi/Wt_lo [N,K] fp16 (transposed, hi/lo split)
__global__ void conv_w_t(const float* __restrict__ W, _Float16* __restrict__ hi,
                         _Float16* __restrict__ lo, int K, int N) {
    int idx = blockIdx.x * blockDim.x + threadIdx.x;
    if (idx >= K * N) return;
    int n = idx / K, k = idx - n * K;
    float v = W[(size_t)k * N + n];
    _Float16 h = (_Float16)v;
    hi[(size_t)n * K + k] = h;
    lo[(size_t)n * K + k] = (_Float16)(v - (float)h);
}

// ---------------- fp16 MFMA GEMM: C = A @ (Wh+Wl)^T ----------------
// A [M,K] fp16 row-major; Wh/Wl [N,K] fp16 row-major (transposed weights).
// MODE 1: out -> fp32;  MODE 2: out -> fp16.
#define TM 128
#define TN 128
#define TK 32
template <int MODE>
__global__ __launch_bounds__(256) void gemm_bt(
        const _Float16* __restrict__ A,
        const _Float16* __restrict__ Bh, const _Float16* __restrict__ Bl,
        const float* __restrict__ bias,
        float* __restrict__ out_f, _Float16* __restrict__ out_h16,
        int M, int N, int K, int act) {
    __shared__ __align__(16) _Float16 sA[TM * TK], sBh[TN * TK], sBl[TN * TK];
    int tid = threadIdx.x;
    int wave = tid >> 6, lane = tid & 63;
    int m0 = blockIdx.y * TM, n0 = blockIdx.x * TN;
    int wm = wave >> 1, wn = wave & 1;           // 2x2 waves, each 64x64
    int srow = lane >> 2;
    int skel = (lane & 3) * 8;
    int fr = lane & 15, quad = lane >> 4;

    f32x4 acc[4][4];
#pragma unroll
    for (int i = 0; i < 4; i++)
#pragma unroll
        for (int j = 0; j < 4; j++) acc[i][j] = (f32x4){0.f, 0.f, 0.f, 0.f};

    for (int k0 = 0; k0 < K; k0 += TK) {
        __syncthreads();
#pragma unroll
        for (int c = 0; c < 2; c++) {
            int chunk = wave * 2 + c;
            int r = chunk * 16 + srow;
            int gmA = m0 + r; if (gmA >= M) gmA = M - 1;
            int gnB = n0 + r;
            size_t aoff = (size_t)gmA * K + k0 + skel;
            size_t boff = (size_t)gnB * K + k0 + skel;
            int ldso = chunk * 512;              // halfs (1 KB chunks)
            async16(A + aoff, &sA[ldso]);
            async16(Bh + boff, &sBh[ldso]);
            async16(Bl + boff, &sBl[ldso]);
        }
        __syncthreads();

        f16x8 fa[4], fbh[4], fbl[4];
#pragma unroll
        for (int i = 0; i < 4; i++) {
            int ra = (wm * 64 + i * 16 + fr) * TK + quad * 8;
            int rb = (wn * 64 + i * 16 + fr) * TK + quad * 8;
            fa[i]  = *(const f16x8*)&sA[ra];
            fbh[i] = *(const f16x8*)&sBh[rb];
            fbl[i] = *(const f16x8*)&sBl[rb];
        }
#pragma unroll
        for (int i = 0; i < 4; i++)
#pragma unroll
            for (int j = 0; j < 4; j++) {
                acc[i][j] = __builtin_amdgcn_mfma_f32_16x16x32_f16(fa[i], fbl[j], acc[i][j], 0, 0, 0);
                acc[i][j] = __builtin_amdgcn_mfma_f32_16x16x32_f16(fa[i], fbh[j], acc[i][j], 0, 0, 0);
            }
    }

#pragma unroll
    for (int i = 0; i < 4; i++)
#pragma unroll
        for (int r = 0; r < 4; r++) {
            int gm = m0 + wm * 64 + i * 16 + quad * 4 + r;
            if (gm >= M) continue;
#pragma unroll
            for (int j = 0; j < 4; j++) {
                int gn = n0 + wn * 64 + j * 16 + fr;
                float v = acc[i][j][r];
                if (bias) v += bias[gn];
                if (act == 1) v = fmaxf(v, 0.f);
                size_t o = (size_t)gm * N + gn;
                if (MODE == 1) out_f[o] = v;
                else           out_h16[o] = (_Float16)v;
            }
        }
}

// ---------------- attention coefficients (fp16 h) ----------------
__global__ void attn_coef_h(const _Float16* __restrict__ h, const float* __restrict__ a_src,
                            const float* __restrict__ a_dst, float* __restrict__ al_s,
                            float* __restrict__ al_d, int N, int H, int C) {
    int n = blockIdx.x;
    int w = threadIdx.x >> 6;
    int lane = threadIdx.x & 63;
    size_t base = ((size_t)n * H + w) * C;
    float ss = 0.f, sd = 0.f;
    for (int c = lane; c < C; c += 64) {
        float v = (float)h[base + c];
        ss += v * a_src[w * C + c];
        sd += v * a_dst[w * C + c];
    }
#pragma unroll
    for (int off = 32; off > 0; off >>= 1) {
        ss += __shfl_down(ss, off);
        sd += __shfl_down(sd, off);
    }
    if (lane == 0) {
        al_s[n * H + w] = ss;
        al_d[n * H + w] = sd;
    }
}

// ---------------- edge weights + denominators ----------------
// one wave per node; lane = slot*H + head (SLOTS = 64/H edge slots).
template <int H>
__global__ void edge_weights(const float* __restrict__ al_s, const float* __restrict__ al_d,
                             const int* __restrict__ indptr, const int* __restrict__ esrc,
                             float* __restrict__ wgt, float* __restrict__ denom, int N) {
    const int SLOTS = 64 / H;
    int n = (blockIdx.x * blockDim.x + threadIdx.x) >> 6;
    int lane = threadIdx.x & 63;
    if (n >= N) return;
    int head = lane & (H - 1);
    int slot = lane / H;
    float ald = al_d[n * H + head];
    float dsum = 0.f;
    int beg = indptr[n], end = indptr[n + 1];
    for (int base = beg; base < end; base += SLOTS) {
        int idx = base + slot;
        if (idx < end) {
            int s = esrc[idx];
            float e = al_s[s * H + head] + ald;
            e = e > 0.f ? e : 0.2f * e;          // leaky_relu 0.2
            e = fminf(e, 60.f);
            float w = __expf(e);
            wgt[(size_t)idx * H + head] = w;
            dsum += w;
        }
    }
#pragma unroll
    for (int off = H; off < 64; off <<= 1) dsum += __shfl_xor(dsum, off);
    if (lane < H) denom[n * H + lane] = dsum;
}

// ---------------- weighted-gather aggregation (4-edge unrolled) ----------------
// one wave per node; lane owns CT consecutive halfs of the C_ALL = CT*64 row.
template <int CT, int H>
__global__ void gat_aggregate_w(const _Float16* __restrict__ h,
                                const float* __restrict__ wgt, const float* __restrict__ denom,
                                const int* __restrict__ indptr, const int* __restrict__ esrc,
                                const float* __restrict__ bias,
                                _Float16* __restrict__ oh,
                                int N, int act) {
    typedef _Float16 hvec __attribute__((ext_vector_type(CT)));
    const int C_ALL = CT * 64;
    int n = (blockIdx.x * blockDim.x + threadIdx.x) >> 6;
    int lane = threadIdx.x & 63;
    if (n >= N) return;
    int head = (lane * H) >> 6;
    float acc[CT];
#pragma unroll
    for (int k = 0; k < CT; k++) acc[k] = 0.f;

    int beg = indptr[n], end = indptr[n + 1];   // >=1 edge (self loop)
    int idx = beg;
    for (; idx + 4 <= end; idx += 4) {
        int s0 = esrc[idx], s1 = esrc[idx + 1], s2 = esrc[idx + 2], s3 = esrc[idx + 3];
        float w0 = wgt[(size_t)idx * H + head];
        float w1 = wgt[(size_t)(idx + 1) * H + head];
        float w2 = wgt[(size_t)(idx + 2) * H + head];
        float w3 = wgt[(size_t)(idx + 3) * H + head];
        hvec v0 = *(const hvec*)(h + (size_t)s0 * C_ALL + lane * CT);
        hvec v1 = *(const hvec*)(h + (size_t)s1 * C_ALL + lane * CT);
        hvec v2 = *(const hvec*)(h + (size_t)s2 * C_ALL + lane * CT);
        hvec v3 = *(const hvec*)(h + (size_t)s3 * C_ALL + lane * CT);
#pragma unroll
        for (int k = 0; k < CT; k++) acc[k] += w0 * (float)v0[k];
#pragma unroll
        for (int k = 0; k < CT; k++) acc[k] += w1 * (float)v1[k];
#pragma unroll
        for (int k = 0; k < CT; k++) acc[k] += w2 * (float)v2[k];
#pragma unroll
        for (int k = 0; k < CT; k++) acc[k] += w3 * (float)v3[k];
    }
    for (; idx < end; ++idx) {
        int s0 = esrc[idx];
        float w0 = wgt[(size_t)idx * H + head];
        hvec v0 = *(const hvec*)(h + (size_t)s0 * C_ALL + lane * CT);
#pragma unroll
        for (int k = 0; k < CT; k++) acc[k] += w0 * (float)v0[k];
    }
    float inv = 1.f / (denom[n * H + head] + 1e-16f);
    size_t ob = (size_t)n * C_ALL + lane * CT;
    const float* bp = bias + lane * CT;
    hvec o;
#pragma unroll
    for (int k = 0; k < CT; k++) {
        float v = acc[k] * inv + bp[k];
        if (act == 1) v = v > 0.f ? v : (__expf(v) - 1.f);   // elu
        o[k] = (_Float16)v;
    }
    *(hvec*)(oh + ob) = o;
}

extern "C" void kernel_launch(void* const* d_in, const int* in_sizes, int n_in,
                              void* d_out, int out_size, void* d_ws, size_t ws_size,
                              hipStream_t stream) {
    const float* x   = (const float*)d_in[0];
    const int*   ei  = (const int*)d_in[1];
    const float* W1  = (const float*)d_in[2];
    const float* as1 = (const float*)d_in[3];
    const float* ad1 = (const float*)d_in[4];
    const float* b1  = (const float*)d_in[5];
    const float* W2  = (const float*)d_in[6];
    const float* as2 = (const float*)d_in[7];
    const float* ad2 = (const float*)d_in[8];
    const float* b2  = (const float*)d_in[9];
    const float* W3  = (const float*)d_in[10];
    const float* as3 = (const float*)d_in[11];
    const float* ad3 = (const float*)d_in[12];
    const float* b3  = (const float*)d_in[13];
    const float* M1  = (const float*)d_in[14];
    const float* mb1 = (const float*)d_in[15];
    const float* M2  = (const float*)d_in[16];
    const float* mb2 = (const float*)d_in[17];
    const float* M3  = (const float*)d_in[18];
    const float* mb3 = (const float*)d_in[19];
    float* out = (float*)d_out;

    const int N = in_sizes[0] / IN_F;   // 50000
    const int E = in_sizes[1] / 2;      // 800000
    const int* src = ei;
    const int* dst = ei + E;

    char* ws = (char*)d_ws;
    auto alloc = [&](size_t bytes) { char* p = ws; ws += (bytes + 255) & ~(size_t)255; return p; };
    _Float16* H16 = (_Float16*)alloc((size_t)N * CATF * 2);  // GEMM output (pre-aggregation)
    _Float16* P16 = (_Float16*)alloc((size_t)N * CATF * 2);  // aggregate output / GEMM A
    float* al_s = (float*)alloc((size_t)N * HEADS * 4);
    float* al_d = (float*)alloc((size_t)N * HEADS * 4);
    float* wgt  = (float*)alloc((size_t)(E + N) * HEADS * 4);
    float* denom = (float*)alloc((size_t)N * HEADS * 4);
    int* cnt    = (int*)alloc((size_t)N * 4);
    int* pos    = (int*)alloc((size_t)N * 4);
    int* indptr = (int*)alloc((size_t)(N + 1) * 4);
    int* esrc   = (int*)alloc((size_t)(E + N) * 4);
    int* bsum   = (int*)alloc(256 * 4);
    auto walloc = [&](int k, int n, _Float16*& h, _Float16*& l) {
        h = (_Float16*)alloc((size_t)k * n * 2);
        l = (_Float16*)alloc((size_t)k * n * 2);
    };
    _Float16 *W1h, *W1l, *W2h, *W2l, *W3h, *W3l, *M1h, *M1l, *M2h, *M2l, *M3h, *M3l;
    walloc(IN_F, CATF, W1h, W1l);
    walloc(CATF, CATF, W2h, W2l);
    walloc(CATF, OUT_F, W3h, W3l);
    walloc(OUT_F, 2 * HIDC, M1h, M1l);
    walloc(2 * HIDC, HIDC, M2h, M2l);
    walloc(HIDC, OUT_F, M3h, M3l);

    // ---- CSR build ----
    const int nb = (N + 255) / 256;   // 196
    init_counts<<<(N + 255) / 256, 256, 0, stream>>>(cnt, N);
    count_dst<<<(E + 255) / 256, 256, 0, stream>>>(dst, E, cnt);
    scan_partial<<<nb, 256, 0, stream>>>(cnt, indptr, bsum, N);
    scan_bsums<<<1, 256, 0, stream>>>(bsum, nb);
    add_carry<<<nb, 256, 0, stream>>>(indptr, pos, bsum, N, E + N);
    scatter_edges<<<(E + N + 255) / 256, 256, 0, stream>>>(src, dst, E, N, pos, esrc);

    // ---- weight conversion + transpose ----
    auto convw = [&](const float* W, _Float16* h, _Float16* l, int K, int Nc) {
        conv_w_t<<<(K * Nc + 255) / 256, 256, 0, stream>>>(W, h, l, K, Nc);
    };
    convw(W1, W1h, W1l, IN_F, CATF);
    convw(W2, W2h, W2l, CATF, CATF);
    convw(W3, W3h, W3l, CATF, OUT_F);
    convw(M1, M1h, M1l, OUT_F, 2 * HIDC);
    convw(M2, M2h, M2l, 2 * HIDC, HIDC);
    convw(M3, M3h, M3l, HIDC, OUT_F);

    auto gemm_h16 = [&](const _Float16* Ap, const _Float16* Bhp, const _Float16* Blp,
                        const float* bias, _Float16* oh, int M, int Nc, int K, int act) {
        dim3 grid(Nc / TN, (M + TM - 1) / TM);
        gemm_bt<2><<<grid, 256, 0, stream>>>(Ap, Bhp, Blp, bias, nullptr, oh, M, Nc, K, act);
    };

    const int gwav = (N + 3) / 4;   // blocks of 4 waves, one wave per node

    // ---- input conversion: x -> P16 [N,256] ----
    conv_h16<<<((long)N * IN_F / 4 + 255) / 256, 256, 0, stream>>>(x, P16, (long)N * IN_F / 4);

    // ---- GAT layer 1 ----
    gemm_h16(P16, W1h, W1l, nullptr, H16, N, CATF, IN_F, 0);
    attn_coef_h<<<N, HEADS * 64, 0, stream>>>(H16, as1, ad1, al_s, al_d, N, HEADS, HIDC);
    edge_weights<HEADS><<<gwav, 256, 0, stream>>>(al_s, al_d, indptr, esrc, wgt, denom, N);
    gat_aggregate_w<8, HEADS><<<gwav, 256, 0, stream>>>(H16, wgt, denom, indptr, esrc,
                                                        b1, P16, N, 1);
    // ---- GAT layer 2 ----
    gemm_h16(P16, W2h, W2l, nullptr, H16, N, CATF, CATF, 0);
    attn_coef_h<<<N, HEADS * 64, 0, stream>>>(H16, as2, ad2, al_s, al_d, N, HEADS, HIDC);
    edge_weights<HEADS><<<gwav, 256, 0, stream>>>(al_s, al_d, indptr, esrc, wgt, denom, N);
    gat_aggregate_w<8, HEADS><<<gwav, 256, 0, stream>>>(H16, wgt, denom, indptr, esrc,
                                                        b2, P16, N, 1);
    // ---- GAT layer 3 (1 head, C=256, no ELU) ----
    gemm_h16(P16, W3h, W3l, nullptr, H16, N, OUT_F, CATF, 0);
    attn_coef_h<<<N, 64, 0, stream>>>(H16, as3, ad3, al_s, al_d, N, 1, OUT_F);
    edge_weights<1><<<gwav, 256, 0, stream>>>(al_s, al_d, indptr, esrc, wgt, denom, N);
    gat_aggregate_w<4, 1><<<gwav, 256, 0, stream>>>(H16, wgt, denom, indptr, esrc,
                                                    b3, P16, N, 0);
    // ---- MLP ----
    _Float16* Q16 = H16;                        // [N,256] relu out
    _Float16* R16 = P16 + (size_t)N * OUT_F;    // [N,128] second-half of P16 space (unused)
    gemm_h16(P16, M1h, M1l, mb1, Q16, N, 2 * HIDC, OUT_F, 1);   // relu
    gemm_h16(Q16, M2h, M2l, mb2, R16, N, HIDC, 2 * HIDC, 1);    // relu
    {
        dim3 grid(OUT_F / TN, (N + TM - 1) / TM);
        gemm_bt<1><<<grid, 256, 0, stream>>>(R16, M3h, M3l, mb3, out, nullptr,
                                             N, OUT_F, HIDC, 0);
    }
}

// Round 7
// 836.559 us; speedup vs baseline: 3.1158x; 1.1317x over previous
//
#include <hip/hip_runtime.h>
#include <cstdint>
#include <cstddef>

#define HEADS  4
#define HIDC   128
#define CATF   512
#define IN_F   256
#define OUT_F  256

typedef _Float16 f16x8 __attribute__((ext_vector_type(8)));
typedef _Float16 f16x4 __attribute__((ext_vector_type(4)));
typedef float f32x4  __attribute__((ext_vector_type(4)));

__device__ __forceinline__ void async16(const void* g, void* l) {
    __builtin_amdgcn_global_load_lds((const __attribute__((address_space(1))) void*)g,
                                     (__attribute__((address_space(3))) void*)l, 16, 0, 0);
}

// ---------------- CSR build ----------------
__global__ void init_counts(int* cnt, int N) {
    int i = blockIdx.x * blockDim.x + threadIdx.x;
    if (i < N) cnt[i] = 1;  // self loop
}

__global__ void count_dst(const int* __restrict__ dst, int E, int* cnt) {
    int i = blockIdx.x * blockDim.x + threadIdx.x;
    if (i < E) atomicAdd(&cnt[dst[i]], 1);
}

__global__ void scan_partial(const int* __restrict__ cnt, int* excl, int* bsum, int N) {
    __shared__ int tmp[256];
    int i = blockIdx.x * 256 + threadIdx.x;
    int v = (i < N) ? cnt[i] : 0;
    tmp[threadIdx.x] = v;
    __syncthreads();
    for (int off = 1; off < 256; off <<= 1) {
        int t = ((int)threadIdx.x >= off) ? tmp[threadIdx.x - off] : 0;
        __syncthreads();
        tmp[threadIdx.x] += t;
        __syncthreads();
    }
    if (i < N) excl[i] = tmp[threadIdx.x] - v;
    if (threadIdx.x == 255) bsum[blockIdx.x] = tmp[255];
}

__global__ void scan_bsums(int* bsum, int nb) {   // single block, nb <= 256
    __shared__ int tmp[256];
    int v = ((int)threadIdx.x < nb) ? bsum[threadIdx.x] : 0;
    tmp[threadIdx.x] = v;
    __syncthreads();
    for (int off = 1; off < 256; off <<= 1) {
        int t = ((int)threadIdx.x >= off) ? tmp[threadIdx.x - off] : 0;
        __syncthreads();
        tmp[threadIdx.x] += t;
        __syncthreads();
    }
    if ((int)threadIdx.x < nb) bsum[threadIdx.x] = tmp[threadIdx.x] - v;
}

__global__ void add_carry(int* indptr, int* pos, const int* __restrict__ bsum, int N, int total) {
    int i = blockIdx.x * blockDim.x + threadIdx.x;
    if (i < N) {
        int v = indptr[i] + bsum[i >> 8];
        indptr[i] = v;
        pos[i] = v;
    }
    if (i == 0) indptr[N] = total;
}

__global__ void scatter_edges(const int* __restrict__ src, const int* __restrict__ dst,
                              int E, int N, int* pos, int* esrc) {
    int i = blockIdx.x * blockDim.x + threadIdx.x;
    int total = E + N;
    if (i >= total) return;
    int s, d;
    if (i < E) { s = src[i]; d = dst[i]; }
    else       { s = i - E;  d = s; }
    int p = atomicAdd(&pos[d], 1);
    esrc[p] = s;
}

// ---------------- fp32 -> fp16 ----------------
__global__ void conv_h16(const float* __restrict__ in, _Float16* __restrict__ out, long n4) {
    long i = (long)blockIdx.x * blockDim.x + threadIdx.x;
    if (i >= n4) return;
    float4 v = ((const float4*)in)[i];
    f16x4 o = { (_Float16)v.x, (_Float16)v.y, (_Float16)v.z, (_Float16)v.w };
    ((f16x4*)out)[i] = o;
}

// all weights: W[K,N] fp32 -> Wt_hi/Wt_lo [N,K] fp16 (transposed, hi/lo split)
struct WDesc { const float* W; _Float16* hi; _Float16* lo; int K; int N; int off; };
struct WPack { WDesc d[6]; int total; };
__global__ void conv_w_all(WPack p) {
    int idx = blockIdx.x * blockDim.x + threadIdx.x;
    if (idx >= p.total) return;
    int wi = 0;
    while (wi < 5 && idx >= p.d[wi + 1].off) wi++;
    const WDesc& w = p.d[wi];
    int li = idx - w.off;
    int n = li / w.K, k = li - n * w.K;
    float v = w.W[(size_t)k * w.N + n];
    _Float16 h = (_Float16)v;
    w.hi[(size_t)n * w.K + k] = h;
    if (w.lo) w.lo[(size_t)n * w.K + k] = (_Float16)(v - (float)h);
}

__global__ void zero2(float* a, float* b, int n) {
    int i = blockIdx.x * blockDim.x + threadIdx.x;
    if (i < n) { a[i] = 0.f; b[i] = 0.f; }
}

// ---------------- fp16 MFMA GEMM: C = A @ W^T (+ fused attention coefs) ----------------
// A [M,K] fp16; Bh/Bl [N,K] fp16 (transposed weights). NMF=1: hi only; NMF=2: hi+lo.
// MODE 1: fp32 out; MODE 2: fp16 out.
// ATTN 0: none; 1: al_s[gm*4 + n0/128] = sum_c v*asrc[gn] (col-block == head);
//      2: atomicAdd(&al_s[gm], ...) (single head spanning multiple col-blocks).
#define TM 128
#define TN 128
#define TK 32
template <int MODE, int NMF, int ATTN>
__global__ __launch_bounds__(256) void gemm_bt(
        const _Float16* __restrict__ A,
        const _Float16* __restrict__ Bh, const _Float16* __restrict__ Bl,
        const float* __restrict__ bias,
        float* __restrict__ out_f, _Float16* __restrict__ out_h16,
        const float* __restrict__ asrc, const float* __restrict__ adst,
        float* __restrict__ al_s, float* __restrict__ al_d,
        int M, int N, int K, int act) {
    __shared__ __align__(16) _Float16 sA[TM * TK], sBh[TN * TK];
    __shared__ __align__(16) _Float16 sBl[NMF == 2 ? TN * TK : 16];
    __shared__ float sred[ATTN ? TM * 4 : 4];   // [row][s/d][wn]
    int tid = threadIdx.x;
    int wave = tid >> 6, lane = tid & 63;
    int m0 = blockIdx.y * TM, n0 = blockIdx.x * TN;
    int wm = wave >> 1, wn = wave & 1;           // 2x2 waves, each 64x64
    int srow = lane >> 2;
    int skel = (lane & 3) * 8;
    int fr = lane & 15, quad = lane >> 4;

    f32x4 acc[4][4];
#pragma unroll
    for (int i = 0; i < 4; i++)
#pragma unroll
        for (int j = 0; j < 4; j++) acc[i][j] = (f32x4){0.f, 0.f, 0.f, 0.f};

    for (int k0 = 0; k0 < K; k0 += TK) {
        __syncthreads();
#pragma unroll
        for (int c = 0; c < 2; c++) {
            int chunk = wave * 2 + c;
            int r = chunk * 16 + srow;
            int gmA = m0 + r; if (gmA >= M) gmA = M - 1;
            int gnB = n0 + r;
            size_t aoff = (size_t)gmA * K + k0 + skel;
            size_t boff = (size_t)gnB * K + k0 + skel;
            int ldso = chunk * 512;              // halfs (1 KB chunks)
            async16(A + aoff, &sA[ldso]);
            async16(Bh + boff, &sBh[ldso]);
            if (NMF == 2) async16(Bl + boff, &sBl[ldso]);
        }
        __syncthreads();

        f16x8 fa[4], fbh[4], fbl[4];
#pragma unroll
        for (int i = 0; i < 4; i++) {
            int ra = (wm * 64 + i * 16 + fr) * TK + quad * 8;
            int rb = (wn * 64 + i * 16 + fr) * TK + quad * 8;
            fa[i]  = *(const f16x8*)&sA[ra];
            fbh[i] = *(const f16x8*)&sBh[rb];
            if (NMF == 2) fbl[i] = *(const f16x8*)&sBl[rb];
        }
#pragma unroll
        for (int i = 0; i < 4; i++)
#pragma unroll
            for (int j = 0; j < 4; j++) {
                if (NMF == 2)
                    acc[i][j] = __builtin_amdgcn_mfma_f32_16x16x32_f16(fa[i], fbl[j], acc[i][j], 0, 0, 0);
                acc[i][j] = __builtin_amdgcn_mfma_f32_16x16x32_f16(fa[i], fbh[j], acc[i][j], 0, 0, 0);
            }
    }

    float avs[4], avd[4];
    if (ATTN) {
#pragma unroll
        for (int j = 0; j < 4; j++) {
            int gn = n0 + wn * 64 + j * 16 + fr;
            avs[j] = asrc[gn];
            avd[j] = adst[gn];
        }
        __syncthreads();   // done with sA; sred may alias activity timing
    }

#pragma unroll
    for (int i = 0; i < 4; i++)
#pragma unroll
        for (int r = 0; r < 4; r++) {
            int gm = m0 + wm * 64 + i * 16 + quad * 4 + r;
            if (gm >= M) continue;     // uniform across the 16-lane fr group
            float ps = 0.f, pd = 0.f;
#pragma unroll
            for (int j = 0; j < 4; j++) {
                int gn = n0 + wn * 64 + j * 16 + fr;
                float v = acc[i][j][r];
                if (bias) v += bias[gn];
                if (act == 1) v = fmaxf(v, 0.f);
                size_t o = (size_t)gm * N + gn;
                if (MODE == 1) out_f[o] = v;
                else           out_h16[o] = (_Float16)v;
                if (ATTN) { ps += v * avs[j]; pd += v * avd[j]; }
            }
            if (ATTN) {
#pragma unroll
                for (int off = 1; off < 16; off <<= 1) {
                    ps += __shfl_xor(ps, off);
                    pd += __shfl_xor(pd, off);
                }
                if (fr == 0) {
                    int lrow = wm * 64 + i * 16 + quad * 4 + r;
                    sred[lrow * 4 + 0 * 2 + wn] = ps;
                    sred[lrow * 4 + 1 * 2 + wn] = pd;
                }
            }
        }

    if (ATTN) {
        __syncthreads();
        if (tid < TM) {
            int gm = m0 + tid;
            if (gm < M) {
                float s = sred[tid * 4 + 0] + sred[tid * 4 + 1];
                float d = sred[tid * 4 + 2] + sred[tid * 4 + 3];
                if (ATTN == 1) {
                    int head = n0 >> 7;
                    al_s[gm * HEADS + head] = s;
                    al_d[gm * HEADS + head] = d;
                } else {
                    atomicAdd(&al_s[gm], s);
                    atomicAdd(&al_d[gm], d);
                }
            }
        }
    }
}

// ---------------- edge weights + denominators ----------------
template <int H>
__global__ void edge_weights(const float* __restrict__ al_s, const float* __restrict__ al_d,
                             const int* __restrict__ indptr, const int* __restrict__ esrc,
                             float* __restrict__ wgt, float* __restrict__ denom, int N) {
    const int SLOTS = 64 / H;
    int n = (blockIdx.x * blockDim.x + threadIdx.x) >> 6;
    int lane = threadIdx.x & 63;
    if (n >= N) return;
    int head = lane & (H - 1);
    int slot = lane / H;
    float ald = al_d[n * H + head];
    float dsum = 0.f;
    int beg = indptr[n], end = indptr[n + 1];
    for (int base = beg; base < end; base += SLOTS) {
        int idx = base + slot;
        if (idx < end) {
            int s = esrc[idx];
            float e = al_s[s * H + head] + ald;
            e = e > 0.f ? e : 0.2f * e;          // leaky_relu 0.2
            e = fminf(e, 60.f);
            float w = __expf(e);
            wgt[(size_t)idx * H + head] = w;
            dsum += w;
        }
    }
#pragma unroll
    for (int off = H; off < 64; off <<= 1) dsum += __shfl_xor(dsum, off);
    if (lane < H) denom[n * H + lane] = dsum;
}

// ---------------- weighted-gather aggregation (8-edge unrolled) ----------------
template <int CT, int H>
__global__ void gat_aggregate_w(const _Float16* __restrict__ h,
                                const float* __restrict__ wgt, const float* __restrict__ denom,
                                const int* __restrict__ indptr, const int* __restrict__ esrc,
                                const float* __restrict__ bias,
                                _Float16* __restrict__ oh,
                                int N, int act) {
    typedef _Float16 hvec __attribute__((ext_vector_type(CT)));
    const int C_ALL = CT * 64;
    int n = (blockIdx.x * blockDim.x + threadIdx.x) >> 6;
    int lane = threadIdx.x & 63;
    if (n >= N) return;
    int head = (lane * H) >> 6;
    float acc[CT];
#pragma unroll
    for (int k = 0; k < CT; k++) acc[k] = 0.f;

    int beg = indptr[n], end = indptr[n + 1];   // >=1 edge (self loop)
    int idx = beg;
    for (; idx + 8 <= end; idx += 8) {
        int s[8]; float w[8]; hvec v[8];
#pragma unroll
        for (int u = 0; u < 8; u++) s[u] = esrc[idx + u];
#pragma unroll
        for (int u = 0; u < 8; u++) w[u] = wgt[(size_t)(idx + u) * H + head];
#pragma unroll
        for (int u = 0; u < 8; u++) v[u] = *(const hvec*)(h + (size_t)s[u] * C_ALL + lane * CT);
#pragma unroll
        for (int u = 0; u < 8; u++)
#pragma unroll
            for (int k = 0; k < CT; k++) acc[k] += w[u] * (float)v[u][k];
    }
    for (; idx + 2 <= end; idx += 2) {
        int s0 = esrc[idx], s1 = esrc[idx + 1];
        float w0 = wgt[(size_t)idx * H + head];
        float w1 = wgt[(size_t)(idx + 1) * H + head];
        hvec v0 = *(const hvec*)(h + (size_t)s0 * C_ALL + lane * CT);
        hvec v1 = *(const hvec*)(h + (size_t)s1 * C_ALL + lane * CT);
#pragma unroll
        for (int k = 0; k < CT; k++) acc[k] += w0 * (float)v0[k];
#pragma unroll
        for (int k = 0; k < CT; k++) acc[k] += w1 * (float)v1[k];
    }
    if (idx < end) {
        int s0 = esrc[idx];
        float w0 = wgt[(size_t)idx * H + head];
        hvec v0 = *(const hvec*)(h + (size_t)s0 * C_ALL + lane * CT);
#pragma unroll
        for (int k = 0; k < CT; k++) acc[k] += w0 * (float)v0[k];
    }
    float inv = 1.f / (denom[n * H + head] + 1e-16f);
    size_t ob = (size_t)n * C_ALL + lane * CT;
    const float* bp = bias + lane * CT;
    hvec o;
#pragma unroll
    for (int k = 0; k < CT; k++) {
        float v = acc[k] * inv + bp[k];
        if (act == 1) v = v > 0.f ? v : (__expf(v) - 1.f);   // elu
        o[k] = (_Float16)v;
    }
    *(hvec*)(oh + ob) = o;
}

extern "C" void kernel_launch(void* const* d_in, const int* in_sizes, int n_in,
                              void* d_out, int out_size, void* d_ws, size_t ws_size,
                              hipStream_t stream) {
    const float* x   = (const float*)d_in[0];
    const int*   ei  = (const int*)d_in[1];
    const float* W1  = (const float*)d_in[2];
    const float* as1 = (const float*)d_in[3];
    const float* ad1 = (const float*)d_in[4];
    const float* b1  = (const float*)d_in[5];
    const float* W2  = (const float*)d_in[6];
    const float* as2 = (const float*)d_in[7];
    const float* ad2 = (const float*)d_in[8];
    const float* b2  = (const float*)d_in[9];
    const float* W3  = (const float*)d_in[10];
    const float* as3 = (const float*)d_in[11];
    const float* ad3 = (const float*)d_in[12];
    const float* b3  = (const float*)d_in[13];
    const float* M1  = (const float*)d_in[14];
    const float* mb1 = (const float*)d_in[15];
    const float* M2  = (const float*)d_in[16];
    const float* mb2 = (const float*)d_in[17];
    const float* M3  = (const float*)d_in[18];
    const float* mb3 = (const float*)d_in[19];
    float* out = (float*)d_out;

    const int N = in_sizes[0] / IN_F;   // 50000
    const int E = in_sizes[1] / 2;      // 800000
    const int* src = ei;
    const int* dst = ei + E;

    char* ws = (char*)d_ws;
    auto alloc = [&](size_t bytes) { char* p = ws; ws += (bytes + 255) & ~(size_t)255; return p; };
    _Float16* H16 = (_Float16*)alloc((size_t)N * CATF * 2);  // GEMM output (pre-aggregation)
    _Float16* P16 = (_Float16*)alloc((size_t)N * CATF * 2);  // aggregate output / GEMM A
    float* al_s = (float*)alloc((size_t)N * HEADS * 4);
    float* al_d = (float*)alloc((size_t)N * HEADS * 4);
    float* wgt  = (float*)alloc((size_t)(E + N) * HEADS * 4);
    float* denom = (float*)alloc((size_t)N * HEADS * 4);
    int* cnt    = (int*)alloc((size_t)N * 4);
    int* pos    = (int*)alloc((size_t)N * 4);
    int* indptr = (int*)alloc((size_t)(N + 1) * 4);
    int* esrc   = (int*)alloc((size_t)(E + N) * 4);
    int* bsum   = (int*)alloc(256 * 4);
    auto walloc = [&](int k, int n, _Float16*& h, _Float16*& l, bool need_lo) {
        h = (_Float16*)alloc((size_t)k * n * 2);
        l = need_lo ? (_Float16*)alloc((size_t)k * n * 2) : nullptr;
    };
    _Float16 *W1h, *W1l, *W2h, *W2l, *W3h, *W3l, *M1h, *M1l, *M2h, *M2l, *M3h, *M3l;
    walloc(IN_F, CATF, W1h, W1l, false);
    walloc(CATF, CATF, W2h, W2l, false);
    walloc(CATF, OUT_F, W3h, W3l, false);
    walloc(OUT_F, 2 * HIDC, M1h, M1l, true);
    walloc(2 * HIDC, HIDC, M2h, M2l, true);
    walloc(HIDC, OUT_F, M3h, M3l, true);

    // ---- CSR build ----
    const int nb = (N + 255) / 256;   // 196
    init_counts<<<(N + 255) / 256, 256, 0, stream>>>(cnt, N);
    count_dst<<<(E + 255) / 256, 256, 0, stream>>>(dst, E, cnt);
    scan_partial<<<nb, 256, 0, stream>>>(cnt, indptr, bsum, N);
    scan_bsums<<<1, 256, 0, stream>>>(bsum, nb);
    add_carry<<<nb, 256, 0, stream>>>(indptr, pos, bsum, N, E + N);
    scatter_edges<<<(E + N + 255) / 256, 256, 0, stream>>>(src, dst, E, N, pos, esrc);

    // ---- weight conversion + transpose (one kernel) ----
    {
        WPack p;
        int off = 0;
        auto setd = [&](int i, const float* W, _Float16* h, _Float16* l, int K, int Nc) {
            p.d[i] = WDesc{W, h, l, K, Nc, off};
            off += K * Nc;
        };
        setd(0, W1, W1h, W1l, IN_F, CATF);
        setd(1, W2, W2h, W2l, CATF, CATF);
        setd(2, W3, W3h, W3l, CATF, OUT_F);
        setd(3, M1, M1h, M1l, OUT_F, 2 * HIDC);
        setd(4, M2, M2h, M2l, 2 * HIDC, HIDC);
        setd(5, M3, M3h, M3l, HIDC, OUT_F);
        p.total = off;
        conv_w_all<<<(off + 255) / 256, 256, 0, stream>>>(p);
    }

    // gemm helpers
    auto gemm_gat = [&](const _Float16* Ap, const _Float16* Bhp, _Float16* oh,
                        const float* asrc, const float* adst, int M_, int Nc, int K, int attn_mode) {
        dim3 grid(Nc / TN, (M_ + TM - 1) / TM);
        if (attn_mode == 1)
            gemm_bt<2, 1, 1><<<grid, 256, 0, stream>>>(Ap, Bhp, nullptr, nullptr, nullptr, oh,
                                                       asrc, adst, al_s, al_d, M_, Nc, K, 0);
        else
            gemm_bt<2, 1, 2><<<grid, 256, 0, stream>>>(Ap, Bhp, nullptr, nullptr, nullptr, oh,
                                                       asrc, adst, al_s, al_d, M_, Nc, K, 0);
    };
    auto gemm_mlp16 = [&](const _Float16* Ap, const _Float16* Bhp, const _Float16* Blp,
                          const float* bias, _Float16* oh, int M_, int Nc, int K, int act) {
        dim3 grid(Nc / TN, (M_ + TM - 1) / TM);
        gemm_bt<2, 2, 0><<<grid, 256, 0, stream>>>(Ap, Bhp, Blp, bias, nullptr, oh,
                                                   nullptr, nullptr, nullptr, nullptr, M_, Nc, K, act);
    };

    const int gwav = (N + 3) / 4;   // blocks of 4 waves, one wave per node

    // ---- input conversion: x -> P16 [N,256] ----
    conv_h16<<<((long)N * IN_F / 4 + 255) / 256, 256, 0, stream>>>(x, P16, (long)N * IN_F / 4);

    // ---- GAT layer 1 ----
    gemm_gat(P16, W1h, H16, as1, ad1, N, CATF, IN_F, 1);
    edge_weights<HEADS><<<gwav, 256, 0, stream>>>(al_s, al_d, indptr, esrc, wgt, denom, N);
    gat_aggregate_w<8, HEADS><<<gwav, 256, 0, stream>>>(H16, wgt, denom, indptr, esrc,
                                                        b1, P16, N, 1);
    // ---- GAT layer 2 ----
    gemm_gat(P16, W2h, H16, as2, ad2, N, CATF, CATF, 1);
    edge_weights<HEADS><<<gwav, 256, 0, stream>>>(al_s, al_d, indptr, esrc, wgt, denom, N);
    gat_aggregate_w<8, HEADS><<<gwav, 256, 0, stream>>>(H16, wgt, denom, indptr, esrc,
                                                        b2, P16, N, 1);
    // ---- GAT layer 3 (1 head, C=256, atomic attn accumulation) ----
    zero2<<<(N + 255) / 256, 256, 0, stream>>>(al_s, al_d, N);
    gemm_gat(P16, W3h, H16, as3, ad3, N, OUT_F, CATF, 2);
    edge_weights<1><<<gwav, 256, 0, stream>>>(al_s, al_d, indptr, esrc, wgt, denom, N);
    gat_aggregate_w<4, 1><<<gwav, 256, 0, stream>>>(H16, wgt, denom, indptr, esrc,
                                                    b3, P16, N, 0);
    // ---- MLP ----
    _Float16* Q16 = H16;                        // [N,256] relu out
    _Float16* R16 = P16 + (size_t)N * OUT_F;    // [N,128] second-half of P16 space (unused)
    gemm_mlp16(P16, M1h, M1l, mb1, Q16, N, 2 * HIDC, OUT_F, 1);   // relu
    gemm_mlp16(Q16, M2h, M2l, mb2, R16, N, HIDC, 2 * HIDC, 1);    // relu
    {
        dim3 grid(OUT_F / TN, (N + TM - 1) / TM);
        gemm_bt<1, 2, 0><<<grid, 256, 0, stream>>>(R16, M3h, M3l, mb3, out, nullptr,
                                                   nullptr, nullptr, nullptr, nullptr,
                                                   N, OUT_F, HIDC, 0);
    }
}